// Round 14
// baseline (618.808 us; speedup 1.0000x reference)
//
#include <hip/hip_runtime.h>

#define NN 100000
#define NE 3200000
#define NB 1021        // buckets
#define BNODES 98      // nodes per bucket (98*1021 >= NN)
#define NBLK 256       // partition blocks
#define CH 12500       // edges per partition block (NBLK*CH == NE)
#define NCHUNK 8       // src chunks; chunk == XCD via blockIdx&7
#define NPB 400        // nodes per group in aggp
#define NGRP 256       // groups; NGRP*NPB >= NN

typedef unsigned int uint;
typedef __attribute__((ext_vector_type(8))) short short8v;
typedef __attribute__((ext_vector_type(4))) float float4v;
typedef __attribute__((ext_vector_type(4))) uint uint4v;

// ---- bf16 helpers (RTNE) ----
__device__ inline uint bfr(float f) {
  uint u = __float_as_uint(f);
  return (u + 0x7fffu + ((u >> 16) & 1u)) >> 16;
}
__device__ inline uint packbf(float a, float b) { return bfr(a) | (bfr(b) << 16); }
__device__ inline void addq(uint4 q, float* a) {
  uint u[4] = {q.x, q.y, q.z, q.w};
#pragma unroll
  for (int j = 0; j < 4; ++j) {
    a[2 * j]     += __uint_as_float(u[j] << 16);
    a[2 * j + 1] += __uint_as_float(u[j] & 0xffff0000u);
  }
}
// non-temporal 16B helpers (avoid L2 pollution for stream-once data)
__device__ inline uint4 ntload4(const uint4* p) {
  uint4v v = __builtin_nontemporal_load((const uint4v*)p);
  return make_uint4(v.x, v.y, v.z, v.w);
}
__device__ inline void ntstore4(uint4* p, uint4 q) {
  uint4v v = {q.x, q.y, q.z, q.w};
  __builtin_nontemporal_store(v, (uint4v*)p);
}
// chunk = s / 12500 via magic multiply (exact for s < 2^17)
__device__ inline int chunk8(int s) {
  return (int)(((unsigned long long)(uint)s * 343598ull) >> 32);
}

// ---------------- P1: per-block bucket histogram ----------------
__global__ __launch_bounds__(256) void pcount_kernel(const int* __restrict__ dst,
                                                     int* __restrict__ cntmat) {
  __shared__ int cnt[NB];
  int bk = blockIdx.x, tid = threadIdx.x;
  for (int j = tid; j < NB; j += 256) cnt[j] = 0;
  __syncthreads();
  int base = bk * CH;
  for (int i = base + tid * 4; i < base + CH; i += 1024) {
    int4 d4 = *(const int4*)&dst[i];
    atomicAdd(&cnt[(uint)d4.x / (uint)BNODES], 1);
    atomicAdd(&cnt[(uint)d4.y / (uint)BNODES], 1);
    atomicAdd(&cnt[(uint)d4.z / (uint)BNODES], 1);
    atomicAdd(&cnt[(uint)d4.w / (uint)BNODES], 1);
  }
  __syncthreads();
  for (int j = tid; j < NB; j += 256) cntmat[(size_t)j * NBLK + bk] = cnt[j];
}

// ---------------- P2a: bucket totals ----------------
__global__ __launch_bounds__(256) void rowsum_kernel(const int* __restrict__ cntmat,
                                                     int* __restrict__ btotal) {
  int b = blockIdx.x, t = threadIdx.x;
  int v = cntmat[(size_t)b * NBLK + t];
#pragma unroll
  for (int off = 32; off >= 1; off >>= 1) v += __shfl_xor(v, off, 64);
  __shared__ int ws[4];
  if ((t & 63) == 0) ws[t >> 6] = v;
  __syncthreads();
  if (t == 0) btotal[b] = ws[0] + ws[1] + ws[2] + ws[3];
}

// ---------------- P2b: scan bucket totals -> bases ----------------
__global__ __launch_bounds__(1024) void bucket_scan_kernel(const int* __restrict__ btotal,
                                                           int* __restrict__ bbase) {
  __shared__ int sh[1024];
  int i = threadIdx.x;
  int v = (i < NB) ? btotal[i] : 0;
  sh[i] = v;
  __syncthreads();
  for (int off = 1; off < 1024; off <<= 1) {
    int t = (i >= off) ? sh[i - off] : 0;
    __syncthreads();
    sh[i] += t;
    __syncthreads();
  }
  if (i < NB) bbase[i] = sh[i] - v;
}

// ---------------- P2c: per-(bucket,block) offsets ----------------
__global__ __launch_bounds__(256) void offsets_kernel(const int* __restrict__ cntmat,
                                                      const int* __restrict__ bbase,
                                                      int* __restrict__ offmat) {
  __shared__ int sh[256];
  int b = blockIdx.x, t = threadIdx.x;
  int v = cntmat[(size_t)b * NBLK + t];
  sh[t] = v;
  __syncthreads();
  for (int off = 1; off < 256; off <<= 1) {
    int u = (t >= off) ? sh[t - off] : 0;
    __syncthreads();
    sh[t] += u;
    __syncthreads();
  }
  offmat[(size_t)b * NBLK + t] = bbase[b] + sh[t] - v;
}

// ---------------- P3: scatter into bucket-contiguous store (packed 4B) ----------------
__global__ __launch_bounds__(256) void pscatter_kernel(const int* __restrict__ src,
                                                       const int* __restrict__ dst,
                                                       const int* __restrict__ offmat,
                                                       int* __restrict__ store) {
  __shared__ int lcur[NB];
  int bk = blockIdx.x, tid = threadIdx.x;
  for (int j = tid; j < NB; j += 256) lcur[j] = offmat[(size_t)j * NBLK + bk];
  __syncthreads();
  int base = bk * CH;
  for (int i = base + tid * 4; i < base + CH; i += 1024) {
    int4 d4 = *(const int4*)&dst[i];
    int4 s4 = *(const int4*)&src[i];
    int dd[4] = {d4.x, d4.y, d4.z, d4.w};
    int ss[4] = {s4.x, s4.y, s4.z, s4.w};
#pragma unroll
    for (int j = 0; j < 4; ++j) {
      uint b = (uint)dd[j] / (uint)BNODES;
      int dl = dd[j] - (int)(b * BNODES);
      int pos = atomicAdd(&lcur[b], 1);
      store[pos] = ss[j] | (dl << 17);
    }
  }
}

// ---------------- P4: per-bucket chunk-major CSR + rcp[c][node] + dinv ----------------
__global__ __launch_bounds__(256) void build_kernel(const int* __restrict__ btotal,
                                                    const int* __restrict__ bbase,
                                                    const int* __restrict__ store,
                                                    int* __restrict__ rcp,
                                                    float* __restrict__ dinv,
                                                    int* __restrict__ csr_src) {
  __shared__ int cnt2[NCHUNK * BNODES];
  __shared__ int excl2[NCHUNK * BNODES];
  int b = blockIdx.x, tid = threadIdx.x;
  int nb0 = b * BNODES;
  int nn = min(BNODES, NN - nb0);
  for (int j = tid; j < NCHUNK * BNODES; j += 256) cnt2[j] = 0;
  __syncthreads();
  int sz = btotal[b], bb = bbase[b];
  const int* bs = store + bb;
  for (int e = tid; e < sz; e += 256) {
    int p = bs[e];
    int dl = (int)((uint)p >> 17);
    int s = p & 0x1FFFF;
    atomicAdd(&cnt2[chunk8(s) * BNODES + dl], 1);
  }
  __syncthreads();
  if (tid == 0) {
    int run = 0;
    for (int j = 0; j < NCHUNK * BNODES; ++j) { excl2[j] = run; run += cnt2[j]; }
  }
  __syncthreads();
  for (int j = tid; j < nn; j += 256) {
    int deg = 0;
#pragma unroll
    for (int c = 0; c < NCHUNK; ++c) {
      int bin = c * BNODES + j;
      rcp[(size_t)c * NN + nb0 + j] = ((bb + excl2[bin]) << 8) | cnt2[bin];
      deg += cnt2[bin];
    }
    dinv[nb0 + j] = rsqrtf((float)(deg + 1));
  }
  __syncthreads();
  for (int j = tid; j < NCHUNK * BNODES; j += 256) cnt2[j] = 0;  // cursors
  __syncthreads();
  for (int e = tid; e < sz; e += 256) {
    int p = bs[e];
    int dl = (int)((uint)p >> 17);
    int s = p & 0x1FFFF;
    int bin = chunk8(s) * BNODES + dl;
    int pos = atomicAdd(&cnt2[bin], 1);
    csr_src[bb + excl2[bin] + pos] = s;
  }
}

// ---------------- W -> bf16 transposed: WT[col][k] = bf16(W[k][col]), K=128 ----------------
__global__ __launch_bounds__(256) void wconv_kernel(const float* __restrict__ W,
                                                    ushort* __restrict__ WT, int N) {
  int idx = blockIdx.x * 256 + threadIdx.x;
  if (idx < 128 * N) {
    int col = idx >> 7;
    int k = idx & 127;
    WT[idx] = (ushort)bfr(W[(size_t)k * N + col]);
  }
}

// ---------------- MFMA GEMM (layer 1): C[M][N](bf16) = (X@W)*dinv ----------------
template <int N, bool INBF>
__global__ __launch_bounds__(256) void gemm_mfma_kernel(const void* __restrict__ Xv,
                                                        const ushort* __restrict__ WT,
                                                        const float* __restrict__ dinv,
                                                        ushort* __restrict__ C, int M) {
  constexpr int K = 128;
  constexpr int LDK = K + 8;
  __shared__ ushort Xs[64 * LDK];
  __shared__ ushort Ws[N * LDK];
  int tid = threadIdx.x;
  int row0 = blockIdx.x * 64;

#pragma unroll
  for (int i = 0; i < 4; ++i) {
    int idx = (tid + i * 256) * 8;
    int r = idx >> 7, c = idx & 127;
    uint4 v = make_uint4(0, 0, 0, 0);
    if (row0 + r < M) {
      if (INBF) {
        v = *(const uint4*)((const ushort*)Xv + (size_t)(row0 + r) * K + c);
      } else {
        const float* Xf = (const float*)Xv + (size_t)(row0 + r) * K + c;
        float4 f0 = *(const float4*)Xf;
        float4 f1 = *(const float4*)(Xf + 4);
        v.x = packbf(f0.x, f0.y); v.y = packbf(f0.z, f0.w);
        v.z = packbf(f1.x, f1.y); v.w = packbf(f1.z, f1.w);
      }
    }
    *(uint4*)&Xs[r * LDK + c] = v;
  }
#pragma unroll
  for (int i = 0; i < N * K / 2048; ++i) {
    int idx = (tid + i * 256) * 8;
    int col = idx >> 7, k = idx & 127;
    *(uint4*)&Ws[col * LDK + k] = *(const uint4*)&WT[col * K + k];
  }
  __syncthreads();

  int w = tid >> 6, lane = tid & 63;
  int l15 = lane & 15, lhi = lane >> 4;
  constexpr int NF = N / 16;
  float4v acc[NF];
#pragma unroll
  for (int f = 0; f < NF; ++f) acc[f] = (float4v)(0.f);

  const ushort* xbase = &Xs[(w * 16 + l15) * LDK + lhi * 8];
#pragma unroll
  for (int s = 0; s < 4; ++s) {
    short8v a = *(const short8v*)(xbase + s * 32);
#pragma unroll
    for (int f = 0; f < NF; ++f) {
      short8v b = *(const short8v*)&Ws[(f * 16 + l15) * LDK + s * 32 + lhi * 8];
      acc[f] = __builtin_amdgcn_mfma_f32_16x16x32_bf16(a, b, acc[f], 0, 0, 0);
    }
  }

  int rbase = row0 + w * 16 + lhi * 4;
  float dv[4];
#pragma unroll
  for (int j = 0; j < 4; ++j) dv[j] = (rbase + j < M) ? dinv[rbase + j] : 0.f;
#pragma unroll
  for (int f = 0; f < NF; ++f) {
#pragma unroll
    for (int j = 0; j < 4; ++j) {
      int row = rbase + j;
      if (row < M) C[(size_t)row * N + f * 16 + l15] = (ushort)bfr(acc[f][j] * dv[j]);
    }
  }
}

// ---- XCD-partitioned partial aggregation: chunk = blockIdx&7 (== XCD under RR dispatch) ----
// nt loads for csr (stream-once) + nt stores for P keep L2 reserved for the Tp slice.
template <int LPN>
__global__ __launch_bounds__(256) void aggp_kernel(const uint4* __restrict__ Tq,
                                                   const int* __restrict__ rcp,
                                                   const int* __restrict__ csr_src,
                                                   ushort* __restrict__ P, int n) {
  int c = blockIdx.x & 7;
  int g = blockIdx.x >> 3;
  constexpr int SPB = 256 / LPN;
  int lane = threadIdx.x & (LPN - 1);
  int slot = threadIdx.x / LPN;
  uint4* Pq = (uint4*)P + (size_t)c * n * LPN;
  const int* rcp_c = rcp + (size_t)c * NN;
  constexpr int ITERS = (NPB + SPB - 1) / SPB;
  for (int it = 0; it < ITERS; ++it) {
    int off = it * SPB + slot;
    if (off >= NPB) break;
    int node = g * NPB + off;
    if (node >= n) break;
    int v = __builtin_nontemporal_load(&rcp_c[node]);
    int lo = v >> 8, hi = lo + (v & 255);
    float a[8];
#pragma unroll
    for (int j = 0; j < 8; ++j) a[j] = 0.f;
    if (chunk8(node) == c) addq(Tq[(size_t)node * LPN + lane], a);
    int e = lo;
    for (; e + 4 <= hi; e += 4) {
      int s0 = __builtin_nontemporal_load(&csr_src[e]);
      int s1 = __builtin_nontemporal_load(&csr_src[e + 1]);
      int s2 = __builtin_nontemporal_load(&csr_src[e + 2]);
      int s3 = __builtin_nontemporal_load(&csr_src[e + 3]);
      uint4 q0 = Tq[(size_t)s0 * LPN + lane];
      uint4 q1 = Tq[(size_t)s1 * LPN + lane];
      uint4 q2 = Tq[(size_t)s2 * LPN + lane];
      uint4 q3 = Tq[(size_t)s3 * LPN + lane];
      addq(q0, a); addq(q1, a); addq(q2, a); addq(q3, a);
    }
    for (; e < hi; ++e) {
      int s = __builtin_nontemporal_load(&csr_src[e]);
      addq(Tq[(size_t)s * LPN + lane], a);
    }
    uint4 st;
    st.x = packbf(a[0], a[1]);
    st.y = packbf(a[2], a[3]);
    st.z = packbf(a[4], a[5]);
    st.w = packbf(a[6], a[7]);
    ntstore4(&Pq[(size_t)node * LPN + lane], st);
  }
}

// ---- fused GEMM: h = relu(dn*sum_c P_c + b); C = (h @ W)*dinv, bf16 ----
template <int N>
__global__ __launch_bounds__(256) void gemm_fused_kernel(const ushort* __restrict__ P,
                                                         const ushort* __restrict__ WT,
                                                         const float* __restrict__ dinv,
                                                         const float* __restrict__ bias,
                                                         ushort* __restrict__ C, int M) {
  constexpr int K = 128;
  constexpr int LDK = K + 8;
  __shared__ ushort Xs[64 * LDK];
  __shared__ ushort Ws[N * LDK];
  int tid = threadIdx.x;
  int row0 = blockIdx.x * 64;
  const uint4* Pq = (const uint4*)P;
  size_t ps = (size_t)M * 16;  // uint4 stride per partial

  {
    int l = tid & 15;
    int rb = tid >> 4;
    float4 bv0 = *(const float4*)&bias[l * 8];
    float4 bv1 = *(const float4*)&bias[l * 8 + 4];
    float bb[8] = {bv0.x, bv0.y, bv0.z, bv0.w, bv1.x, bv1.y, bv1.z, bv1.w};
#pragma unroll
    for (int i = 0; i < 4; ++i) {
      int r = rb + i * 16;
      int row = row0 + r;
      uint4 st = make_uint4(0, 0, 0, 0);
      if (row < M) {
        float a[8];
#pragma unroll
        for (int j = 0; j < 8; ++j) a[j] = 0.f;
#pragma unroll
        for (int c = 0; c < 8; ++c)
          addq(ntload4(&Pq[(size_t)c * ps + (size_t)row * 16 + l]), a);
        float dn = dinv[row];
        float h[8];
#pragma unroll
        for (int j = 0; j < 8; ++j) h[j] = fmaxf(fmaf(dn, a[j], bb[j]), 0.f);
        st.x = packbf(h[0], h[1]);
        st.y = packbf(h[2], h[3]);
        st.z = packbf(h[4], h[5]);
        st.w = packbf(h[6], h[7]);
      }
      *(uint4*)&Xs[r * LDK + l * 8] = st;
    }
  }
#pragma unroll
  for (int i = 0; i < N * K / 2048; ++i) {
    int idx = (tid + i * 256) * 8;
    int col = idx >> 7, k = idx & 127;
    *(uint4*)&Ws[col * LDK + k] = *(const uint4*)&WT[col * K + k];
  }
  __syncthreads();

  int w = tid >> 6, lane = tid & 63;
  int l15 = lane & 15, lhi = lane >> 4;
  constexpr int NF = N / 16;
  float4v acc[NF];
#pragma unroll
  for (int f = 0; f < NF; ++f) acc[f] = (float4v)(0.f);

  const ushort* xbase = &Xs[(w * 16 + l15) * LDK + lhi * 8];
#pragma unroll
  for (int s = 0; s < 4; ++s) {
    short8v a = *(const short8v*)(xbase + s * 32);
#pragma unroll
    for (int f = 0; f < NF; ++f) {
      short8v b = *(const short8v*)&Ws[(f * 16 + l15) * LDK + s * 32 + lhi * 8];
      acc[f] = __builtin_amdgcn_mfma_f32_16x16x32_bf16(a, b, acc[f], 0, 0, 0);
    }
  }

  int rbase = row0 + w * 16 + lhi * 4;
  float dv[4];
#pragma unroll
  for (int j = 0; j < 4; ++j) dv[j] = (rbase + j < M) ? dinv[rbase + j] : 0.f;
#pragma unroll
  for (int f = 0; f < NF; ++f) {
#pragma unroll
    for (int j = 0; j < 4; ++j) {
      int row = rbase + j;
      if (row < M) C[(size_t)row * N + f * 16 + l15] = (ushort)bfr(acc[f][j] * dv[j]);
    }
  }
}

// ---- layer-3 reduce: h3 = dn*sum_c P3_c + b3 -> hemb fp32; out = h3@Wout + bout ----
__global__ __launch_bounds__(256) void reduce3_kernel(const ushort* __restrict__ P,
                                                      const float* __restrict__ dinv,
                                                      const float* __restrict__ b3,
                                                      const float* __restrict__ Wout,
                                                      const float* __restrict__ bout,
                                                      float* __restrict__ Hemb,
                                                      float* __restrict__ Out, int n) {
  int t = blockIdx.x * 256 + threadIdx.x;
  int node = t >> 3;
  int lane = t & 7;
  if (node >= n) return;
  const uint4* Pq = (const uint4*)P;
  size_t ps = (size_t)n * 8;
  float a[8];
#pragma unroll
  for (int j = 0; j < 8; ++j) a[j] = 0.f;
#pragma unroll
  for (int c = 0; c < 8; ++c) addq(ntload4(&Pq[(size_t)c * ps + (size_t)node * 8 + lane]), a);
  float dn = dinv[node];
  float4 bv0 = *(const float4*)&b3[lane * 8];
  float4 bv1 = *(const float4*)&b3[lane * 8 + 4];
  float bb[8] = {bv0.x, bv0.y, bv0.z, bv0.w, bv1.x, bv1.y, bv1.z, bv1.w};
  float h[8];
#pragma unroll
  for (int j = 0; j < 8; ++j) h[j] = fmaf(dn, a[j], bb[j]);
  float* Hrow = &Hemb[(size_t)node * 64 + lane * 8];
  *(float4*)&Hrow[0] = make_float4(h[0], h[1], h[2], h[3]);
  *(float4*)&Hrow[4] = make_float4(h[4], h[5], h[6], h[7]);
  int k0 = 8 * lane;
  float p0 = 0.f, p1 = 0.f;
#pragma unroll
  for (int j = 0; j < 8; ++j) {
    p0 = fmaf(h[j], Wout[(k0 + j) * 2 + 0], p0);
    p1 = fmaf(h[j], Wout[(k0 + j) * 2 + 1], p1);
  }
#pragma unroll
  for (int off = 4; off >= 1; off >>= 1) {
    p0 += __shfl_xor(p0, off, 8);
    p1 += __shfl_xor(p1, off, 8);
  }
  if (lane == 0) {
    Out[(size_t)node * 2 + 0] = p0 + bout[0];
    Out[(size_t)node * 2 + 1] = p1 + bout[1];
  }
}

// ---- fallback (small ws): direct bf16 gather agg over rcp[c][node] segments ----
__global__ __launch_bounds__(256) void agg_fb128_kernel(const uint4* __restrict__ Tq,
                                                        const int* __restrict__ rcp,
                                                        const int* __restrict__ csr_src,
                                                        const float* __restrict__ dinv,
                                                        const float* __restrict__ bias,
                                                        ushort* __restrict__ H, int n) {
  int t = blockIdx.x * 256 + threadIdx.x;
  int node = t >> 4;
  int lane = t & 15;
  if (node >= n) return;
  float dn = dinv[node];
  float a0[8], a1[8], a2[8], a3[8];
#pragma unroll
  for (int c = 0; c < 8; ++c) { a0[c] = 0.f; a1[c] = 0.f; a2[c] = 0.f; a3[c] = 0.f; }
  addq(Tq[(size_t)node * 16 + lane], a0);
#pragma unroll
  for (int c = 0; c < 8; ++c) {
    int v = rcp[(size_t)c * NN + node];
    int lo = v >> 8, hi = lo + (v & 255);
    int e = lo;
    for (; e + 4 <= hi; e += 4) {
      uint4 q0 = Tq[(size_t)csr_src[e] * 16 + lane];
      uint4 q1 = Tq[(size_t)csr_src[e + 1] * 16 + lane];
      uint4 q2 = Tq[(size_t)csr_src[e + 2] * 16 + lane];
      uint4 q3 = Tq[(size_t)csr_src[e + 3] * 16 + lane];
      addq(q0, a0); addq(q1, a1); addq(q2, a2); addq(q3, a3);
    }
    for (; e < hi; ++e) addq(Tq[(size_t)csr_src[e] * 16 + lane], a0);
  }
  float4 bv0 = *(const float4*)&bias[lane * 8];
  float4 bv1 = *(const float4*)&bias[lane * 8 + 4];
  float bb[8] = {bv0.x, bv0.y, bv0.z, bv0.w, bv1.x, bv1.y, bv1.z, bv1.w};
  float h[8];
#pragma unroll
  for (int c = 0; c < 8; ++c) {
    h[c] = fmaf(dn, (a0[c] + a1[c]) + (a2[c] + a3[c]), bb[c]);
    h[c] = fmaxf(h[c], 0.f);
  }
  uint4 st;
  st.x = packbf(h[0], h[1]);
  st.y = packbf(h[2], h[3]);
  st.z = packbf(h[4], h[5]);
  st.w = packbf(h[6], h[7]);
  *(uint4*)&H[(size_t)node * 128 + lane * 8] = st;
}

__global__ __launch_bounds__(256) void agg_fb64_kernel(const uint4* __restrict__ Tq,
                                                       const int* __restrict__ rcp,
                                                       const int* __restrict__ csr_src,
                                                       const float* __restrict__ dinv,
                                                       const float* __restrict__ bias,
                                                       float* __restrict__ H,
                                                       const float* __restrict__ Wout,
                                                       const float* __restrict__ bout,
                                                       float* __restrict__ Out, int n) {
  int t = blockIdx.x * 256 + threadIdx.x;
  int node = t >> 3;
  int lane = t & 7;
  if (node >= n) return;
  float dn = dinv[node];
  float a0[8], a1[8], a2[8], a3[8];
#pragma unroll
  for (int c = 0; c < 8; ++c) { a0[c] = 0.f; a1[c] = 0.f; a2[c] = 0.f; a3[c] = 0.f; }
  addq(Tq[(size_t)node * 8 + lane], a0);
#pragma unroll
  for (int c = 0; c < 8; ++c) {
    int v = rcp[(size_t)c * NN + node];
    int lo = v >> 8, hi = lo + (v & 255);
    int e = lo;
    for (; e + 4 <= hi; e += 4) {
      uint4 q0 = Tq[(size_t)csr_src[e] * 8 + lane];
      uint4 q1 = Tq[(size_t)csr_src[e + 1] * 8 + lane];
      uint4 q2 = Tq[(size_t)csr_src[e + 2] * 8 + lane];
      uint4 q3 = Tq[(size_t)csr_src[e + 3] * 8 + lane];
      addq(q0, a0); addq(q1, a1); addq(q2, a2); addq(q3, a3);
    }
    for (; e < hi; ++e) addq(Tq[(size_t)csr_src[e] * 8 + lane], a0);
  }
  float4 bv0 = *(const float4*)&bias[lane * 8];
  float4 bv1 = *(const float4*)&bias[lane * 8 + 4];
  float bb[8] = {bv0.x, bv0.y, bv0.z, bv0.w, bv1.x, bv1.y, bv1.z, bv1.w};
  float h[8];
#pragma unroll
  for (int c = 0; c < 8; ++c)
    h[c] = fmaf(dn, (a0[c] + a1[c]) + (a2[c] + a3[c]), bb[c]);
  float* Hrow = &H[(size_t)node * 64 + lane * 8];
  *(float4*)&Hrow[0] = make_float4(h[0], h[1], h[2], h[3]);
  *(float4*)&Hrow[4] = make_float4(h[4], h[5], h[6], h[7]);
  int k0 = 8 * lane;
  float p0 = 0.f, p1 = 0.f;
#pragma unroll
  for (int c = 0; c < 8; ++c) {
    p0 = fmaf(h[c], Wout[(k0 + c) * 2 + 0], p0);
    p1 = fmaf(h[c], Wout[(k0 + c) * 2 + 1], p1);
  }
#pragma unroll
  for (int off = 4; off >= 1; off >>= 1) {
    p0 += __shfl_xor(p0, off, 8);
    p1 += __shfl_xor(p1, off, 8);
  }
  if (lane == 0) {
    Out[(size_t)node * 2 + 0] = p0 + bout[0];
    Out[(size_t)node * 2 + 1] = p1 + bout[1];
  }
}

extern "C" void kernel_launch(void* const* d_in, const int* in_sizes, int n_in,
                              void* d_out, int out_size, void* d_ws, size_t ws_size,
                              hipStream_t stream) {
  const float* x    = (const float*)d_in[0];
  const int*   ei   = (const int*)d_in[1];
  const float* W1   = (const float*)d_in[2];
  const float* b1   = (const float*)d_in[3];
  const float* W2   = (const float*)d_in[4];
  const float* b2   = (const float*)d_in[5];
  const float* W3   = (const float*)d_in[6];
  const float* b3   = (const float*)d_in[7];
  const float* Wout = (const float*)d_in[8];
  const float* bout = (const float*)d_in[9];

  const int n = NN, E = NE;
  const int* srcp = ei;
  const int* dstp = ei + E;

  char* ws = (char*)d_ws;
  int*    cntmat  = (int*)(ws + 0);            // 1,045,504
  int*    btotal  = (int*)(ws + 1045504);      // -> 1,049,600
  int*    bbase   = (int*)(ws + 1049600);      // -> 1,053,696
  int*    offmat  = (int*)(ws + 1053696);      // -> 2,099,200
  float*  dinv    = (float*)(ws + 2099200);    // -> 2,499,200 (pad 16)
  int*    rcp     = (int*)(ws + 2499216);      // 3.2MB -> 5,699,216  (layout [c][node])
  int*    csr_src = (int*)(ws + 5699216);      // 12.8MB -> 18,499,216
  ushort* WT1     = (ushort*)(ws + 18499216);  // 32KB
  ushort* WT2     = (ushort*)(ws + 18531984);  // 32KB
  ushort* WT3     = (ushort*)(ws + 18564752);  // 16KB -> 18,581,136
  ushort* bufT    = (ushort*)(ws + 18581136);  // 25.6MB -> 44,181,136
  ushort* Pbuf    = (ushort*)(ws + 44181136);  // 8 x 25.6MB -> 248,981,136
  int*    store   = (int*)(ws + 44181136);     // 12.8MB, aliases Pbuf (dead after build)

  const size_t PRIMARY_NEED = 248981136ull;
  bool primary = ws_size >= PRIMARY_NEED;

  float* outp = (float*)d_out;
  float* hemb = (float*)d_out + 2 * n;

  // ---- graph build (atomic-free radix partition, chunk-major CSR) ----
  pcount_kernel<<<NBLK, 256, 0, stream>>>(dstp, cntmat);
  rowsum_kernel<<<NB, 256, 0, stream>>>(cntmat, btotal);
  bucket_scan_kernel<<<1, 1024, 0, stream>>>(btotal, bbase);
  offsets_kernel<<<NB, 256, 0, stream>>>(cntmat, bbase, offmat);
  pscatter_kernel<<<NBLK, 256, 0, stream>>>(srcp, dstp, offmat, store);
  build_kernel<<<NB, 256, 0, stream>>>(btotal, bbase, store, rcp, dinv, csr_src);

  wconv_kernel<<<(128 * 128 + 255) / 256, 256, 0, stream>>>(W1, WT1, 128);
  wconv_kernel<<<(128 * 128 + 255) / 256, 256, 0, stream>>>(W2, WT2, 128);
  wconv_kernel<<<(128 * 64 + 255) / 256, 256, 0, stream>>>(W3, WT3, 64);

  int gemmGrid = (n + 63) / 64;

  if (primary) {
    // layer 1
    gemm_mfma_kernel<128, false><<<gemmGrid, 256, 0, stream>>>(x, WT1, dinv, bufT, n);
    aggp_kernel<16><<<NGRP * 8, 256, 0, stream>>>((const uint4*)bufT, rcp, csr_src, Pbuf, n);
    // layer 2 (fused reduce+GEMM)
    gemm_fused_kernel<128><<<gemmGrid, 256, 0, stream>>>(Pbuf, WT2, dinv, b1, bufT, n);
    aggp_kernel<16><<<NGRP * 8, 256, 0, stream>>>((const uint4*)bufT, rcp, csr_src, Pbuf, n);
    // layer 3 (fused reduce+GEMM, 64ch)
    gemm_fused_kernel<64><<<gemmGrid, 256, 0, stream>>>(Pbuf, WT3, dinv, b2, bufT, n);
    aggp_kernel<8><<<NGRP * 8, 256, 0, stream>>>((const uint4*)bufT, rcp, csr_src, Pbuf, n);
    reduce3_kernel<<<(n * 8 + 255) / 256, 256, 0, stream>>>(Pbuf, dinv, b3, Wout, bout,
                                                            hemb, outp, n);
  } else {
    // fallback: R12 structure (direct gather over rcp segments)
    ushort* bufHb = Pbuf;  // only 25.6MB used
    gemm_mfma_kernel<128, false><<<gemmGrid, 256, 0, stream>>>(x, WT1, dinv, bufT, n);
    agg_fb128_kernel<<<(n * 16 + 255) / 256, 256, 0, stream>>>(
        (const uint4*)bufT, rcp, csr_src, dinv, b1, bufHb, n);
    gemm_mfma_kernel<128, true><<<gemmGrid, 256, 0, stream>>>(bufHb, WT2, dinv, bufT, n);
    agg_fb128_kernel<<<(n * 16 + 255) / 256, 256, 0, stream>>>(
        (const uint4*)bufT, rcp, csr_src, dinv, b2, bufHb, n);
    gemm_mfma_kernel<64, true><<<gemmGrid, 256, 0, stream>>>(bufHb, WT3, dinv, bufT, n);
    agg_fb64_kernel<<<(n * 8 + 255) / 256, 256, 0, stream>>>(
        (const uint4*)bufT, rcp, csr_src, dinv, b3, hemb, Wout, bout, outp, n);
  }
}

// Round 15
// 468.346 us; speedup vs baseline: 1.3213x; 1.3213x over previous
//
#include <hip/hip_runtime.h>

#define NN 100000
#define NE 3200000
#define NB 1021        // buckets
#define BNODES 98      // nodes per bucket (98*1021 >= NN)
#define NBLK 256       // partition blocks
#define CH 12500       // edges per partition block (NBLK*CH == NE)
#define NCHUNK 8       // src chunks; chunk == XCD via blockIdx&7
#define NPB 400        // nodes per group in aggp
#define NGRP 256       // groups; NGRP*NPB >= NN

typedef unsigned int uint;
typedef __attribute__((ext_vector_type(8))) short short8v;
typedef __attribute__((ext_vector_type(4))) float float4v;
typedef __attribute__((ext_vector_type(4))) uint uint4v;

// ---- bf16 helpers (RTNE) ----
__device__ inline uint bfr(float f) {
  uint u = __float_as_uint(f);
  return (u + 0x7fffu + ((u >> 16) & 1u)) >> 16;
}
__device__ inline uint packbf(float a, float b) { return bfr(a) | (bfr(b) << 16); }
__device__ inline void addq(uint4 q, float* a) {
  uint u[4] = {q.x, q.y, q.z, q.w};
#pragma unroll
  for (int j = 0; j < 4; ++j) {
    a[2 * j]     += __uint_as_float(u[j] << 16);
    a[2 * j + 1] += __uint_as_float(u[j] & 0xffff0000u);
  }
}
// non-temporal 16B helpers (avoid L2 pollution for stream-once data)
__device__ inline uint4 ntload4(const uint4* p) {
  uint4v v = __builtin_nontemporal_load((const uint4v*)p);
  return make_uint4(v.x, v.y, v.z, v.w);
}
__device__ inline void ntstore4(uint4* p, uint4 q) {
  uint4v v = {q.x, q.y, q.z, q.w};
  __builtin_nontemporal_store(v, (uint4v*)p);
}
// chunk = s / 12500 via magic multiply (exact for s < 2^17)
__device__ inline int chunk8(int s) {
  return (int)(((unsigned long long)(uint)s * 343598ull) >> 32);
}

// ---------------- P1: per-block bucket histogram ----------------
__global__ __launch_bounds__(256) void pcount_kernel(const int* __restrict__ dst,
                                                     int* __restrict__ cntmat) {
  __shared__ int cnt[NB];
  int bk = blockIdx.x, tid = threadIdx.x;
  for (int j = tid; j < NB; j += 256) cnt[j] = 0;
  __syncthreads();
  int base = bk * CH;
  for (int i = base + tid * 4; i < base + CH; i += 1024) {
    int4 d4 = *(const int4*)&dst[i];
    atomicAdd(&cnt[(uint)d4.x / (uint)BNODES], 1);
    atomicAdd(&cnt[(uint)d4.y / (uint)BNODES], 1);
    atomicAdd(&cnt[(uint)d4.z / (uint)BNODES], 1);
    atomicAdd(&cnt[(uint)d4.w / (uint)BNODES], 1);
  }
  __syncthreads();
  for (int j = tid; j < NB; j += 256) cntmat[(size_t)j * NBLK + bk] = cnt[j];
}

// ---------------- P2a: bucket totals ----------------
__global__ __launch_bounds__(256) void rowsum_kernel(const int* __restrict__ cntmat,
                                                     int* __restrict__ btotal) {
  int b = blockIdx.x, t = threadIdx.x;
  int v = cntmat[(size_t)b * NBLK + t];
#pragma unroll
  for (int off = 32; off >= 1; off >>= 1) v += __shfl_xor(v, off, 64);
  __shared__ int ws[4];
  if ((t & 63) == 0) ws[t >> 6] = v;
  __syncthreads();
  if (t == 0) btotal[b] = ws[0] + ws[1] + ws[2] + ws[3];
}

// ---------------- P2b: scan bucket totals -> bases ----------------
__global__ __launch_bounds__(1024) void bucket_scan_kernel(const int* __restrict__ btotal,
                                                           int* __restrict__ bbase) {
  __shared__ int sh[1024];
  int i = threadIdx.x;
  int v = (i < NB) ? btotal[i] : 0;
  sh[i] = v;
  __syncthreads();
  for (int off = 1; off < 1024; off <<= 1) {
    int t = (i >= off) ? sh[i - off] : 0;
    __syncthreads();
    sh[i] += t;
    __syncthreads();
  }
  if (i < NB) bbase[i] = sh[i] - v;
}

// ---------------- P2c: per-(bucket,block) offsets ----------------
__global__ __launch_bounds__(256) void offsets_kernel(const int* __restrict__ cntmat,
                                                      const int* __restrict__ bbase,
                                                      int* __restrict__ offmat) {
  __shared__ int sh[256];
  int b = blockIdx.x, t = threadIdx.x;
  int v = cntmat[(size_t)b * NBLK + t];
  sh[t] = v;
  __syncthreads();
  for (int off = 1; off < 256; off <<= 1) {
    int u = (t >= off) ? sh[t - off] : 0;
    __syncthreads();
    sh[t] += u;
    __syncthreads();
  }
  offmat[(size_t)b * NBLK + t] = bbase[b] + sh[t] - v;
}

// ---------------- P3: scatter into bucket-contiguous store (packed 4B) ----------------
__global__ __launch_bounds__(256) void pscatter_kernel(const int* __restrict__ src,
                                                       const int* __restrict__ dst,
                                                       const int* __restrict__ offmat,
                                                       int* __restrict__ store) {
  __shared__ int lcur[NB];
  int bk = blockIdx.x, tid = threadIdx.x;
  for (int j = tid; j < NB; j += 256) lcur[j] = offmat[(size_t)j * NBLK + bk];
  __syncthreads();
  int base = bk * CH;
  for (int i = base + tid * 4; i < base + CH; i += 1024) {
    int4 d4 = *(const int4*)&dst[i];
    int4 s4 = *(const int4*)&src[i];
    int dd[4] = {d4.x, d4.y, d4.z, d4.w};
    int ss[4] = {s4.x, s4.y, s4.z, s4.w};
#pragma unroll
    for (int j = 0; j < 4; ++j) {
      uint b = (uint)dd[j] / (uint)BNODES;
      int dl = dd[j] - (int)(b * BNODES);
      int pos = atomicAdd(&lcur[b], 1);
      store[pos] = ss[j] | (dl << 17);
    }
  }
}

// ---------------- P4: per-bucket chunk-major CSR + rcp[c][node] + dinv ----------------
__global__ __launch_bounds__(256) void build_kernel(const int* __restrict__ btotal,
                                                    const int* __restrict__ bbase,
                                                    const int* __restrict__ store,
                                                    int* __restrict__ rcp,
                                                    float* __restrict__ dinv,
                                                    int* __restrict__ csr_src) {
  __shared__ int cnt2[NCHUNK * BNODES];
  __shared__ int excl2[NCHUNK * BNODES];
  int b = blockIdx.x, tid = threadIdx.x;
  int nb0 = b * BNODES;
  int nn = min(BNODES, NN - nb0);
  for (int j = tid; j < NCHUNK * BNODES; j += 256) cnt2[j] = 0;
  __syncthreads();
  int sz = btotal[b], bb = bbase[b];
  const int* bs = store + bb;
  for (int e = tid; e < sz; e += 256) {
    int p = bs[e];
    int dl = (int)((uint)p >> 17);
    int s = p & 0x1FFFF;
    atomicAdd(&cnt2[chunk8(s) * BNODES + dl], 1);
  }
  __syncthreads();
  if (tid == 0) {
    int run = 0;
    for (int j = 0; j < NCHUNK * BNODES; ++j) { excl2[j] = run; run += cnt2[j]; }
  }
  __syncthreads();
  for (int j = tid; j < nn; j += 256) {
    int deg = 0;
#pragma unroll
    for (int c = 0; c < NCHUNK; ++c) {
      int bin = c * BNODES + j;
      rcp[(size_t)c * NN + nb0 + j] = ((bb + excl2[bin]) << 8) | cnt2[bin];
      deg += cnt2[bin];
    }
    dinv[nb0 + j] = rsqrtf((float)(deg + 1));
  }
  __syncthreads();
  for (int j = tid; j < NCHUNK * BNODES; j += 256) cnt2[j] = 0;  // cursors
  __syncthreads();
  for (int e = tid; e < sz; e += 256) {
    int p = bs[e];
    int dl = (int)((uint)p >> 17);
    int s = p & 0x1FFFF;
    int bin = chunk8(s) * BNODES + dl;
    int pos = atomicAdd(&cnt2[bin], 1);
    csr_src[bb + excl2[bin] + pos] = s;
  }
}

// ---------------- W -> bf16 transposed: WT[col][k] = bf16(W[k][col]), K=128 ----------------
__global__ __launch_bounds__(256) void wconv_kernel(const float* __restrict__ W,
                                                    ushort* __restrict__ WT, int N) {
  int idx = blockIdx.x * 256 + threadIdx.x;
  if (idx < 128 * N) {
    int col = idx >> 7;
    int k = idx & 127;
    WT[idx] = (ushort)bfr(W[(size_t)k * N + col]);
  }
}

// ---------------- MFMA GEMM (layer 1): C[M][N](bf16) = (X@W)*dinv ----------------
template <int N, bool INBF>
__global__ __launch_bounds__(256) void gemm_mfma_kernel(const void* __restrict__ Xv,
                                                        const ushort* __restrict__ WT,
                                                        const float* __restrict__ dinv,
                                                        ushort* __restrict__ C, int M) {
  constexpr int K = 128;
  constexpr int LDK = K + 8;
  __shared__ ushort Xs[64 * LDK];
  __shared__ ushort Ws[N * LDK];
  int tid = threadIdx.x;
  int row0 = blockIdx.x * 64;

#pragma unroll
  for (int i = 0; i < 4; ++i) {
    int idx = (tid + i * 256) * 8;
    int r = idx >> 7, c = idx & 127;
    uint4 v = make_uint4(0, 0, 0, 0);
    if (row0 + r < M) {
      if (INBF) {
        v = *(const uint4*)((const ushort*)Xv + (size_t)(row0 + r) * K + c);
      } else {
        const float* Xf = (const float*)Xv + (size_t)(row0 + r) * K + c;
        float4 f0 = *(const float4*)Xf;
        float4 f1 = *(const float4*)(Xf + 4);
        v.x = packbf(f0.x, f0.y); v.y = packbf(f0.z, f0.w);
        v.z = packbf(f1.x, f1.y); v.w = packbf(f1.z, f1.w);
      }
    }
    *(uint4*)&Xs[r * LDK + c] = v;
  }
#pragma unroll
  for (int i = 0; i < N * K / 2048; ++i) {
    int idx = (tid + i * 256) * 8;
    int col = idx >> 7, k = idx & 127;
    *(uint4*)&Ws[col * LDK + k] = *(const uint4*)&WT[col * K + k];
  }
  __syncthreads();

  int w = tid >> 6, lane = tid & 63;
  int l15 = lane & 15, lhi = lane >> 4;
  constexpr int NF = N / 16;
  float4v acc[NF];
#pragma unroll
  for (int f = 0; f < NF; ++f) acc[f] = (float4v)(0.f);

  const ushort* xbase = &Xs[(w * 16 + l15) * LDK + lhi * 8];
#pragma unroll
  for (int s = 0; s < 4; ++s) {
    short8v a = *(const short8v*)(xbase + s * 32);
#pragma unroll
    for (int f = 0; f < NF; ++f) {
      short8v b = *(const short8v*)&Ws[(f * 16 + l15) * LDK + s * 32 + lhi * 8];
      acc[f] = __builtin_amdgcn_mfma_f32_16x16x32_bf16(a, b, acc[f], 0, 0, 0);
    }
  }

  int rbase = row0 + w * 16 + lhi * 4;
  float dv[4];
#pragma unroll
  for (int j = 0; j < 4; ++j) dv[j] = (rbase + j < M) ? dinv[rbase + j] : 0.f;
#pragma unroll
  for (int f = 0; f < NF; ++f) {
#pragma unroll
    for (int j = 0; j < 4; ++j) {
      int row = rbase + j;
      if (row < M) C[(size_t)row * N + f * 16 + l15] = (ushort)bfr(acc[f][j] * dv[j]);
    }
  }
}

// ---- XCD-partitioned partial aggregation: chunk = blockIdx&7 (== XCD under RR dispatch) ----
// Regular (cached) loads for rcp/csr (lane-broadcast via L1); NT stores for P
// (keep write-allocate from evicting the L2-resident Tp slice).
template <int LPN>
__global__ __launch_bounds__(256) void aggp_kernel(const uint4* __restrict__ Tq,
                                                   const int* __restrict__ rcp,
                                                   const int* __restrict__ csr_src,
                                                   ushort* __restrict__ P, int n) {
  int c = blockIdx.x & 7;
  int g = blockIdx.x >> 3;
  constexpr int SPB = 256 / LPN;
  int lane = threadIdx.x & (LPN - 1);
  int slot = threadIdx.x / LPN;
  uint4* Pq = (uint4*)P + (size_t)c * n * LPN;
  const int* rcp_c = rcp + (size_t)c * NN;
  constexpr int ITERS = (NPB + SPB - 1) / SPB;
  for (int it = 0; it < ITERS; ++it) {
    int off = it * SPB + slot;
    if (off >= NPB) break;
    int node = g * NPB + off;
    if (node >= n) break;
    int v = rcp_c[node];
    int lo = v >> 8, hi = lo + (v & 255);
    float a[8];
#pragma unroll
    for (int j = 0; j < 8; ++j) a[j] = 0.f;
    if (chunk8(node) == c) addq(Tq[(size_t)node * LPN + lane], a);
    int e = lo;
    for (; e + 4 <= hi; e += 4) {
      int s0 = csr_src[e], s1 = csr_src[e + 1];
      int s2 = csr_src[e + 2], s3 = csr_src[e + 3];
      uint4 q0 = Tq[(size_t)s0 * LPN + lane];
      uint4 q1 = Tq[(size_t)s1 * LPN + lane];
      uint4 q2 = Tq[(size_t)s2 * LPN + lane];
      uint4 q3 = Tq[(size_t)s3 * LPN + lane];
      addq(q0, a); addq(q1, a); addq(q2, a); addq(q3, a);
    }
    for (; e < hi; ++e) addq(Tq[(size_t)csr_src[e] * LPN + lane], a);
    uint4 st;
    st.x = packbf(a[0], a[1]);
    st.y = packbf(a[2], a[3]);
    st.z = packbf(a[4], a[5]);
    st.w = packbf(a[6], a[7]);
    ntstore4(&Pq[(size_t)node * LPN + lane], st);
  }
}

// ---- fused GEMM: h = relu(dn*sum_c P_c + b); C = (h @ W)*dinv, bf16 ----
template <int N>
__global__ __launch_bounds__(256) void gemm_fused_kernel(const ushort* __restrict__ P,
                                                         const ushort* __restrict__ WT,
                                                         const float* __restrict__ dinv,
                                                         const float* __restrict__ bias,
                                                         ushort* __restrict__ C, int M) {
  constexpr int K = 128;
  constexpr int LDK = K + 8;
  __shared__ ushort Xs[64 * LDK];
  __shared__ ushort Ws[N * LDK];
  int tid = threadIdx.x;
  int row0 = blockIdx.x * 64;
  const uint4* Pq = (const uint4*)P;
  size_t ps = (size_t)M * 16;  // uint4 stride per partial

  {
    int l = tid & 15;
    int rb = tid >> 4;
    float4 bv0 = *(const float4*)&bias[l * 8];
    float4 bv1 = *(const float4*)&bias[l * 8 + 4];
    float bb[8] = {bv0.x, bv0.y, bv0.z, bv0.w, bv1.x, bv1.y, bv1.z, bv1.w};
#pragma unroll
    for (int i = 0; i < 4; ++i) {
      int r = rb + i * 16;
      int row = row0 + r;
      uint4 st = make_uint4(0, 0, 0, 0);
      if (row < M) {
        float a[8];
#pragma unroll
        for (int j = 0; j < 8; ++j) a[j] = 0.f;
#pragma unroll
        for (int c = 0; c < 8; ++c)
          addq(ntload4(&Pq[(size_t)c * ps + (size_t)row * 16 + l]), a);
        float dn = dinv[row];
        float h[8];
#pragma unroll
        for (int j = 0; j < 8; ++j) h[j] = fmaxf(fmaf(dn, a[j], bb[j]), 0.f);
        st.x = packbf(h[0], h[1]);
        st.y = packbf(h[2], h[3]);
        st.z = packbf(h[4], h[5]);
        st.w = packbf(h[6], h[7]);
      }
      *(uint4*)&Xs[r * LDK + l * 8] = st;
    }
  }
#pragma unroll
  for (int i = 0; i < N * K / 2048; ++i) {
    int idx = (tid + i * 256) * 8;
    int col = idx >> 7, k = idx & 127;
    *(uint4*)&Ws[col * LDK + k] = *(const uint4*)&WT[col * K + k];
  }
  __syncthreads();

  int w = tid >> 6, lane = tid & 63;
  int l15 = lane & 15, lhi = lane >> 4;
  constexpr int NF = N / 16;
  float4v acc[NF];
#pragma unroll
  for (int f = 0; f < NF; ++f) acc[f] = (float4v)(0.f);

  const ushort* xbase = &Xs[(w * 16 + l15) * LDK + lhi * 8];
#pragma unroll
  for (int s = 0; s < 4; ++s) {
    short8v a = *(const short8v*)(xbase + s * 32);
#pragma unroll
    for (int f = 0; f < NF; ++f) {
      short8v b = *(const short8v*)&Ws[(f * 16 + l15) * LDK + s * 32 + lhi * 8];
      acc[f] = __builtin_amdgcn_mfma_f32_16x16x32_bf16(a, b, acc[f], 0, 0, 0);
    }
  }

  int rbase = row0 + w * 16 + lhi * 4;
  float dv[4];
#pragma unroll
  for (int j = 0; j < 4; ++j) dv[j] = (rbase + j < M) ? dinv[rbase + j] : 0.f;
#pragma unroll
  for (int f = 0; f < NF; ++f) {
#pragma unroll
    for (int j = 0; j < 4; ++j) {
      int row = rbase + j;
      if (row < M) C[(size_t)row * N + f * 16 + l15] = (ushort)bfr(acc[f][j] * dv[j]);
    }
  }
}

// ---- layer-3 reduce: h3 = dn*sum_c P3_c + b3 -> hemb fp32; out = h3@Wout + bout ----
__global__ __launch_bounds__(256) void reduce3_kernel(const ushort* __restrict__ P,
                                                      const float* __restrict__ dinv,
                                                      const float* __restrict__ b3,
                                                      const float* __restrict__ Wout,
                                                      const float* __restrict__ bout,
                                                      float* __restrict__ Hemb,
                                                      float* __restrict__ Out, int n) {
  int t = blockIdx.x * 256 + threadIdx.x;
  int node = t >> 3;
  int lane = t & 7;
  if (node >= n) return;
  const uint4* Pq = (const uint4*)P;
  size_t ps = (size_t)n * 8;
  float a[8];
#pragma unroll
  for (int j = 0; j < 8; ++j) a[j] = 0.f;
#pragma unroll
  for (int c = 0; c < 8; ++c) addq(ntload4(&Pq[(size_t)c * ps + (size_t)node * 8 + lane]), a);
  float dn = dinv[node];
  float4 bv0 = *(const float4*)&b3[lane * 8];
  float4 bv1 = *(const float4*)&b3[lane * 8 + 4];
  float bb[8] = {bv0.x, bv0.y, bv0.z, bv0.w, bv1.x, bv1.y, bv1.z, bv1.w};
  float h[8];
#pragma unroll
  for (int j = 0; j < 8; ++j) h[j] = fmaf(dn, a[j], bb[j]);
  float* Hrow = &Hemb[(size_t)node * 64 + lane * 8];
  *(float4*)&Hrow[0] = make_float4(h[0], h[1], h[2], h[3]);
  *(float4*)&Hrow[4] = make_float4(h[4], h[5], h[6], h[7]);
  int k0 = 8 * lane;
  float p0 = 0.f, p1 = 0.f;
#pragma unroll
  for (int j = 0; j < 8; ++j) {
    p0 = fmaf(h[j], Wout[(k0 + j) * 2 + 0], p0);
    p1 = fmaf(h[j], Wout[(k0 + j) * 2 + 1], p1);
  }
#pragma unroll
  for (int off = 4; off >= 1; off >>= 1) {
    p0 += __shfl_xor(p0, off, 8);
    p1 += __shfl_xor(p1, off, 8);
  }
  if (lane == 0) {
    Out[(size_t)node * 2 + 0] = p0 + bout[0];
    Out[(size_t)node * 2 + 1] = p1 + bout[1];
  }
}

// ---- fallback (small ws): direct bf16 gather agg over rcp[c][node] segments ----
__global__ __launch_bounds__(256) void agg_fb128_kernel(const uint4* __restrict__ Tq,
                                                        const int* __restrict__ rcp,
                                                        const int* __restrict__ csr_src,
                                                        const float* __restrict__ dinv,
                                                        const float* __restrict__ bias,
                                                        ushort* __restrict__ H, int n) {
  int t = blockIdx.x * 256 + threadIdx.x;
  int node = t >> 4;
  int lane = t & 15;
  if (node >= n) return;
  float dn = dinv[node];
  float a0[8], a1[8], a2[8], a3[8];
#pragma unroll
  for (int c = 0; c < 8; ++c) { a0[c] = 0.f; a1[c] = 0.f; a2[c] = 0.f; a3[c] = 0.f; }
  addq(Tq[(size_t)node * 16 + lane], a0);
#pragma unroll
  for (int c = 0; c < 8; ++c) {
    int v = rcp[(size_t)c * NN + node];
    int lo = v >> 8, hi = lo + (v & 255);
    int e = lo;
    for (; e + 4 <= hi; e += 4) {
      uint4 q0 = Tq[(size_t)csr_src[e] * 16 + lane];
      uint4 q1 = Tq[(size_t)csr_src[e + 1] * 16 + lane];
      uint4 q2 = Tq[(size_t)csr_src[e + 2] * 16 + lane];
      uint4 q3 = Tq[(size_t)csr_src[e + 3] * 16 + lane];
      addq(q0, a0); addq(q1, a1); addq(q2, a2); addq(q3, a3);
    }
    for (; e < hi; ++e) addq(Tq[(size_t)csr_src[e] * 16 + lane], a0);
  }
  float4 bv0 = *(const float4*)&bias[lane * 8];
  float4 bv1 = *(const float4*)&bias[lane * 8 + 4];
  float bb[8] = {bv0.x, bv0.y, bv0.z, bv0.w, bv1.x, bv1.y, bv1.z, bv1.w};
  float h[8];
#pragma unroll
  for (int c = 0; c < 8; ++c) {
    h[c] = fmaf(dn, (a0[c] + a1[c]) + (a2[c] + a3[c]), bb[c]);
    h[c] = fmaxf(h[c], 0.f);
  }
  uint4 st;
  st.x = packbf(h[0], h[1]);
  st.y = packbf(h[2], h[3]);
  st.z = packbf(h[4], h[5]);
  st.w = packbf(h[6], h[7]);
  *(uint4*)&H[(size_t)node * 128 + lane * 8] = st;
}

__global__ __launch_bounds__(256) void agg_fb64_kernel(const uint4* __restrict__ Tq,
                                                       const int* __restrict__ rcp,
                                                       const int* __restrict__ csr_src,
                                                       const float* __restrict__ dinv,
                                                       const float* __restrict__ bias,
                                                       float* __restrict__ H,
                                                       const float* __restrict__ Wout,
                                                       const float* __restrict__ bout,
                                                       float* __restrict__ Out, int n) {
  int t = blockIdx.x * 256 + threadIdx.x;
  int node = t >> 3;
  int lane = t & 7;
  if (node >= n) return;
  float dn = dinv[node];
  float a0[8], a1[8], a2[8], a3[8];
#pragma unroll
  for (int c = 0; c < 8; ++c) { a0[c] = 0.f; a1[c] = 0.f; a2[c] = 0.f; a3[c] = 0.f; }
  addq(Tq[(size_t)node * 8 + lane], a0);
#pragma unroll
  for (int c = 0; c < 8; ++c) {
    int v = rcp[(size_t)c * NN + node];
    int lo = v >> 8, hi = lo + (v & 255);
    int e = lo;
    for (; e + 4 <= hi; e += 4) {
      uint4 q0 = Tq[(size_t)csr_src[e] * 8 + lane];
      uint4 q1 = Tq[(size_t)csr_src[e + 1] * 8 + lane];
      uint4 q2 = Tq[(size_t)csr_src[e + 2] * 8 + lane];
      uint4 q3 = Tq[(size_t)csr_src[e + 3] * 8 + lane];
      addq(q0, a0); addq(q1, a1); addq(q2, a2); addq(q3, a3);
    }
    for (; e < hi; ++e) addq(Tq[(size_t)csr_src[e] * 8 + lane], a0);
  }
  float4 bv0 = *(const float4*)&bias[lane * 8];
  float4 bv1 = *(const float4*)&bias[lane * 8 + 4];
  float bb[8] = {bv0.x, bv0.y, bv0.z, bv0.w, bv1.x, bv1.y, bv1.z, bv1.w};
  float h[8];
#pragma unroll
  for (int c = 0; c < 8; ++c)
    h[c] = fmaf(dn, (a0[c] + a1[c]) + (a2[c] + a3[c]), bb[c]);
  float* Hrow = &H[(size_t)node * 64 + lane * 8];
  *(float4*)&Hrow[0] = make_float4(h[0], h[1], h[2], h[3]);
  *(float4*)&Hrow[4] = make_float4(h[4], h[5], h[6], h[7]);
  int k0 = 8 * lane;
  float p0 = 0.f, p1 = 0.f;
#pragma unroll
  for (int c = 0; c < 8; ++c) {
    p0 = fmaf(h[c], Wout[(k0 + c) * 2 + 0], p0);
    p1 = fmaf(h[c], Wout[(k0 + c) * 2 + 1], p1);
  }
#pragma unroll
  for (int off = 4; off >= 1; off >>= 1) {
    p0 += __shfl_xor(p0, off, 8);
    p1 += __shfl_xor(p1, off, 8);
  }
  if (lane == 0) {
    Out[(size_t)node * 2 + 0] = p0 + bout[0];
    Out[(size_t)node * 2 + 1] = p1 + bout[1];
  }
}

extern "C" void kernel_launch(void* const* d_in, const int* in_sizes, int n_in,
                              void* d_out, int out_size, void* d_ws, size_t ws_size,
                              hipStream_t stream) {
  const float* x    = (const float*)d_in[0];
  const int*   ei   = (const int*)d_in[1];
  const float* W1   = (const float*)d_in[2];
  const float* b1   = (const float*)d_in[3];
  const float* W2   = (const float*)d_in[4];
  const float* b2   = (const float*)d_in[5];
  const float* W3   = (const float*)d_in[6];
  const float* b3   = (const float*)d_in[7];
  const float* Wout = (const float*)d_in[8];
  const float* bout = (const float*)d_in[9];

  const int n = NN, E = NE;
  const int* srcp = ei;
  const int* dstp = ei + E;

  char* ws = (char*)d_ws;
  int*    cntmat  = (int*)(ws + 0);            // 1,045,504
  int*    btotal  = (int*)(ws + 1045504);      // -> 1,049,600
  int*    bbase   = (int*)(ws + 1049600);      // -> 1,053,696
  int*    offmat  = (int*)(ws + 1053696);      // -> 2,099,200
  float*  dinv    = (float*)(ws + 2099200);    // -> 2,499,200 (pad 16)
  int*    rcp     = (int*)(ws + 2499216);      // 3.2MB -> 5,699,216  (layout [c][node])
  int*    csr_src = (int*)(ws + 5699216);      // 12.8MB -> 18,499,216
  ushort* WT1     = (ushort*)(ws + 18499216);  // 32KB
  ushort* WT2     = (ushort*)(ws + 18531984);  // 32KB
  ushort* WT3     = (ushort*)(ws + 18564752);  // 16KB -> 18,581,136
  ushort* bufT    = (ushort*)(ws + 18581136);  // 25.6MB -> 44,181,136
  ushort* Pbuf    = (ushort*)(ws + 44181136);  // 8 x 25.6MB -> 248,981,136
  int*    store   = (int*)(ws + 44181136);     // 12.8MB, aliases Pbuf (dead after build)

  const size_t PRIMARY_NEED = 248981136ull;
  bool primary = ws_size >= PRIMARY_NEED;

  float* outp = (float*)d_out;
  float* hemb = (float*)d_out + 2 * n;

  // ---- graph build (atomic-free radix partition, chunk-major CSR) ----
  pcount_kernel<<<NBLK, 256, 0, stream>>>(dstp, cntmat);
  rowsum_kernel<<<NB, 256, 0, stream>>>(cntmat, btotal);
  bucket_scan_kernel<<<1, 1024, 0, stream>>>(btotal, bbase);
  offsets_kernel<<<NB, 256, 0, stream>>>(cntmat, bbase, offmat);
  pscatter_kernel<<<NBLK, 256, 0, stream>>>(srcp, dstp, offmat, store);
  build_kernel<<<NB, 256, 0, stream>>>(btotal, bbase, store, rcp, dinv, csr_src);

  wconv_kernel<<<(128 * 128 + 255) / 256, 256, 0, stream>>>(W1, WT1, 128);
  wconv_kernel<<<(128 * 128 + 255) / 256, 256, 0, stream>>>(W2, WT2, 128);
  wconv_kernel<<<(128 * 64 + 255) / 256, 256, 0, stream>>>(W3, WT3, 64);

  int gemmGrid = (n + 63) / 64;

  if (primary) {
    // layer 1
    gemm_mfma_kernel<128, false><<<gemmGrid, 256, 0, stream>>>(x, WT1, dinv, bufT, n);
    aggp_kernel<16><<<NGRP * 8, 256, 0, stream>>>((const uint4*)bufT, rcp, csr_src, Pbuf, n);
    // layer 2 (fused reduce+GEMM)
    gemm_fused_kernel<128><<<gemmGrid, 256, 0, stream>>>(Pbuf, WT2, dinv, b1, bufT, n);
    aggp_kernel<16><<<NGRP * 8, 256, 0, stream>>>((const uint4*)bufT, rcp, csr_src, Pbuf, n);
    // layer 3 (fused reduce+GEMM, 64ch)
    gemm_fused_kernel<64><<<gemmGrid, 256, 0, stream>>>(Pbuf, WT3, dinv, b2, bufT, n);
    aggp_kernel<8><<<NGRP * 8, 256, 0, stream>>>((const uint4*)bufT, rcp, csr_src, Pbuf, n);
    reduce3_kernel<<<(n * 8 + 255) / 256, 256, 0, stream>>>(Pbuf, dinv, b3, Wout, bout,
                                                            hemb, outp, n);
  } else {
    // fallback: R12 structure (direct gather over rcp segments)
    ushort* bufHb = Pbuf;  // only 25.6MB used
    gemm_mfma_kernel<128, false><<<gemmGrid, 256, 0, stream>>>(x, WT1, dinv, bufT, n);
    agg_fb128_kernel<<<(n * 16 + 255) / 256, 256, 0, stream>>>(
        (const uint4*)bufT, rcp, csr_src, dinv, b1, bufHb, n);
    gemm_mfma_kernel<128, true><<<gemmGrid, 256, 0, stream>>>(bufHb, WT2, dinv, bufT, n);
    agg_fb128_kernel<<<(n * 16 + 255) / 256, 256, 0, stream>>>(
        (const uint4*)bufT, rcp, csr_src, dinv, b2, bufHb, n);
    gemm_mfma_kernel<64, true><<<gemmGrid, 256, 0, stream>>>(bufHb, WT3, dinv, bufT, n);
    agg_fb64_kernel<<<(n * 8 + 255) / 256, 256, 0, stream>>>(
        (const uint4*)bufT, rcp, csr_src, dinv, b3, hemb, Wout, bout, outp, n);
  }
}

// Round 17
// 431.157 us; speedup vs baseline: 1.4352x; 1.0863x over previous
//
#include <hip/hip_runtime.h>

#define NN 100000
#define NE 3200000
#define NB 1021        // buckets
#define BNODES 98      // nodes per bucket (98*1021 >= NN)
#define NBLK 256       // partition blocks
#define CH 12500       // edges per partition block (NBLK*CH == NE)
#define NCHUNK 8       // src chunks; chunk == XCD via blockIdx&7
#define NPB 400        // nodes per group in aggp
#define NGRP 256       // groups; NGRP*NPB >= NN

typedef unsigned int uint;
typedef unsigned char uchar;
typedef __attribute__((ext_vector_type(8))) short short8v;
typedef __attribute__((ext_vector_type(4))) float float4v;
typedef __attribute__((ext_vector_type(2))) float float2v;
typedef __attribute__((ext_vector_type(4))) uint uint4v;

#if defined(__has_builtin)
#if __has_builtin(__builtin_amdgcn_cvt_pk_f32_fp8) && __has_builtin(__builtin_amdgcn_cvt_pk_fp8_f32)
#define HAVE_FP8_CVT 1
#endif
#endif

// ---- bf16 helpers ----
__device__ inline uint bfr(float f) {  // RTNE, scalar (cold paths)
  uint u = __float_as_uint(f);
  return (u + 0x7fffu + ((u >> 16) & 1u)) >> 16;
}
__device__ inline uint pk_bf16(float a, float b) {  // HW packed cvt (hot epilogues)
  uint r;
  asm("v_cvt_pk_bf16_f32 %0, %1, %2" : "=v"(r) : "v"(a), "v"(b));
  return r;
}
__device__ inline void addq(uint4 q, float* a) {  // bf16x8 unpack-add
  uint u[4] = {q.x, q.y, q.z, q.w};
#pragma unroll
  for (int j = 0; j < 4; ++j) {
    a[2 * j]     += __uint_as_float(u[j] << 16);
    a[2 * j + 1] += __uint_as_float(u[j] & 0xffff0000u);
  }
}

// ---- fp8 e4m3 helpers (HI is compile-time: builtins need immediate operands) ----
#ifndef HAVE_FP8_CVT
__device__ inline float f8dec(uint b) {
  uint s = (b >> 7) & 1u, e = (b >> 3) & 15u, m = b & 7u;
  float v;
  if (e == 0) v = (float)m * 0.001953125f;  // subnormal m*2^-9
  else v = __uint_as_float(((e + 120u) << 23) | (m << 20));
  return s ? -v : v;
}
__device__ inline uint f8enc(float f) {
  uint s = __float_as_uint(f) >> 31;
  float af = fabsf(f);
  if (!(af < 448.f)) af = 448.f;
  uint out;
  if (af < 0.015625f) {  // subnormal range (< 2^-6)
    out = (uint)__float2int_rn(af * 512.f);  // 0..8 (8 == min normal)
  } else {
    uint au = __float_as_uint(af);
    int exp = (int)(au >> 23) - 127;
    uint m = au & 0x7fffffu;
    uint mr = (m >> 20) + (((m & 0xfffffu) > 0x80000u) || (((m & 0xfffffu) == 0x80000u) && ((m >> 20) & 1u)) ? 1u : 0u);
    uint E = (uint)(exp + 7);
    if (mr == 8) { mr = 0; E += 1; }
    if (E > 15) { E = 15; mr = 6; }
    out = (E << 3) | mr;
  }
  return out | (s << 7);
}
#endif
template <bool HI>
__device__ inline float2v f8pk(uint u) {
#ifdef HAVE_FP8_CVT
  return __builtin_amdgcn_cvt_pk_f32_fp8(u, HI);
#else
  float2v r;
  r.x = f8dec(HI ? ((u >> 16) & 255u) : (u & 255u));
  r.y = f8dec(HI ? (u >> 24) : ((u >> 8) & 255u));
  return r;
#endif
}
template <bool HI>
__device__ inline uint f8pk_enc(float a, float b, uint old) {
#ifdef HAVE_FP8_CVT
  return __builtin_amdgcn_cvt_pk_fp8_f32(a, b, old, HI);
#else
  uint two = f8enc(a) | (f8enc(b) << 8);
  return HI ? ((old & 0x0000ffffu) | (two << 16)) : ((old & 0xffff0000u) | two);
#endif
}
__device__ inline void addq_f8(uint4 q, float* a) {  // 16 fp8 -> 16 f32 adds
  uint u[4] = {q.x, q.y, q.z, q.w};
#pragma unroll
  for (int j = 0; j < 4; ++j) {
    float2v lo = f8pk<false>(u[j]);
    float2v hi = f8pk<true>(u[j]);
    a[4 * j + 0] += lo.x; a[4 * j + 1] += lo.y;
    a[4 * j + 2] += hi.x; a[4 * j + 3] += hi.y;
  }
}

// non-temporal 16B helpers
__device__ inline uint4 ntload4(const uint4* p) {
  uint4v v = __builtin_nontemporal_load((const uint4v*)p);
  return make_uint4(v.x, v.y, v.z, v.w);
}
__device__ inline void ntstore4(uint4* p, uint4 q) {
  uint4v v = {q.x, q.y, q.z, q.w};
  __builtin_nontemporal_store(v, (uint4v*)p);
}
// chunk = s / 12500 via magic multiply (exact for s < 2^17)
__device__ inline int chunk8(int s) {
  return (int)(((unsigned long long)(uint)s * 343598ull) >> 32);
}

// ---------------- P1: per-block bucket histogram ----------------
__global__ __launch_bounds__(256) void pcount_kernel(const int* __restrict__ dst,
                                                     int* __restrict__ cntmat) {
  __shared__ int cnt[NB];
  int bk = blockIdx.x, tid = threadIdx.x;
  for (int j = tid; j < NB; j += 256) cnt[j] = 0;
  __syncthreads();
  int base = bk * CH;
  for (int i = base + tid * 4; i < base + CH; i += 1024) {
    int4 d4 = *(const int4*)&dst[i];
    atomicAdd(&cnt[(uint)d4.x / (uint)BNODES], 1);
    atomicAdd(&cnt[(uint)d4.y / (uint)BNODES], 1);
    atomicAdd(&cnt[(uint)d4.z / (uint)BNODES], 1);
    atomicAdd(&cnt[(uint)d4.w / (uint)BNODES], 1);
  }
  __syncthreads();
  for (int j = tid; j < NB; j += 256) cntmat[(size_t)j * NBLK + bk] = cnt[j];
}

// ---------------- P2a: bucket totals ----------------
__global__ __launch_bounds__(256) void rowsum_kernel(const int* __restrict__ cntmat,
                                                     int* __restrict__ btotal) {
  int b = blockIdx.x, t = threadIdx.x;
  int v = cntmat[(size_t)b * NBLK + t];
#pragma unroll
  for (int off = 32; off >= 1; off >>= 1) v += __shfl_xor(v, off, 64);
  __shared__ int ws[4];
  if ((t & 63) == 0) ws[t >> 6] = v;
  __syncthreads();
  if (t == 0) btotal[b] = ws[0] + ws[1] + ws[2] + ws[3];
}

// ---------------- P2b: scan bucket totals -> bases ----------------
__global__ __launch_bounds__(1024) void bucket_scan_kernel(const int* __restrict__ btotal,
                                                           int* __restrict__ bbase) {
  __shared__ int sh[1024];
  int i = threadIdx.x;
  int v = (i < NB) ? btotal[i] : 0;
  sh[i] = v;
  __syncthreads();
  for (int off = 1; off < 1024; off <<= 1) {
    int t = (i >= off) ? sh[i - off] : 0;
    __syncthreads();
    sh[i] += t;
    __syncthreads();
  }
  if (i < NB) bbase[i] = sh[i] - v;
}

// ---------------- P2c: per-(bucket,block) offsets ----------------
__global__ __launch_bounds__(256) void offsets_kernel(const int* __restrict__ cntmat,
                                                      const int* __restrict__ bbase,
                                                      int* __restrict__ offmat) {
  __shared__ int sh[256];
  int b = blockIdx.x, t = threadIdx.x;
  int v = cntmat[(size_t)b * NBLK + t];
  sh[t] = v;
  __syncthreads();
  for (int off = 1; off < 256; off <<= 1) {
    int u = (t >= off) ? sh[t - off] : 0;
    __syncthreads();
    sh[t] += u;
    __syncthreads();
  }
  offmat[(size_t)b * NBLK + t] = bbase[b] + sh[t] - v;
}

// ---------------- P3: scatter into bucket-contiguous store (packed 4B) ----------------
__global__ __launch_bounds__(256) void pscatter_kernel(const int* __restrict__ src,
                                                       const int* __restrict__ dst,
                                                       const int* __restrict__ offmat,
                                                       int* __restrict__ store) {
  __shared__ int lcur[NB];
  int bk = blockIdx.x, tid = threadIdx.x;
  for (int j = tid; j < NB; j += 256) lcur[j] = offmat[(size_t)j * NBLK + bk];
  __syncthreads();
  int base = bk * CH;
  for (int i = base + tid * 4; i < base + CH; i += 1024) {
    int4 d4 = *(const int4*)&dst[i];
    int4 s4 = *(const int4*)&src[i];
    int dd[4] = {d4.x, d4.y, d4.z, d4.w};
    int ss[4] = {s4.x, s4.y, s4.z, s4.w};
#pragma unroll
    for (int j = 0; j < 4; ++j) {
      uint b = (uint)dd[j] / (uint)BNODES;
      int dl = dd[j] - (int)(b * BNODES);
      int pos = atomicAdd(&lcur[b], 1);
      store[pos] = ss[j] | (dl << 17);
    }
  }
}

// ---------------- P4: per-bucket chunk-major CSR + rcp[c][node] + dinv ----------------
__global__ __launch_bounds__(256) void build_kernel(const int* __restrict__ btotal,
                                                    const int* __restrict__ bbase,
                                                    const int* __restrict__ store,
                                                    int* __restrict__ rcp,
                                                    float* __restrict__ dinv,
                                                    int* __restrict__ csr_src) {
  __shared__ int cnt2[NCHUNK * BNODES];
  __shared__ int excl2[NCHUNK * BNODES];
  int b = blockIdx.x, tid = threadIdx.x;
  int nb0 = b * BNODES;
  int nn = min(BNODES, NN - nb0);
  for (int j = tid; j < NCHUNK * BNODES; j += 256) cnt2[j] = 0;
  __syncthreads();
  int sz = btotal[b], bb = bbase[b];
  const int* bs = store + bb;
  for (int e = tid; e < sz; e += 256) {
    int p = bs[e];
    int dl = (int)((uint)p >> 17);
    int s = p & 0x1FFFF;
    atomicAdd(&cnt2[chunk8(s) * BNODES + dl], 1);
  }
  __syncthreads();
  if (tid == 0) {
    int run = 0;
    for (int j = 0; j < NCHUNK * BNODES; ++j) { excl2[j] = run; run += cnt2[j]; }
  }
  __syncthreads();
  for (int j = tid; j < nn; j += 256) {
    int deg = 0;
#pragma unroll
    for (int c = 0; c < NCHUNK; ++c) {
      int bin = c * BNODES + j;
      rcp[(size_t)c * NN + nb0 + j] = ((bb + excl2[bin]) << 8) | cnt2[bin];
      deg += cnt2[bin];
    }
    dinv[nb0 + j] = rsqrtf((float)(deg + 1));
  }
  __syncthreads();
  for (int j = tid; j < NCHUNK * BNODES; j += 256) cnt2[j] = 0;  // cursors
  __syncthreads();
  for (int e = tid; e < sz; e += 256) {
    int p = bs[e];
    int dl = (int)((uint)p >> 17);
    int s = p & 0x1FFFF;
    int bin = chunk8(s) * BNODES + dl;
    int pos = atomicAdd(&cnt2[bin], 1);
    csr_src[bb + excl2[bin] + pos] = s;
  }
}

// ---------------- W -> bf16 transposed: WT[col][k] = bf16(W[k][col]), K=128 ----------------
__global__ __launch_bounds__(256) void wconv_kernel(const float* __restrict__ W,
                                                    ushort* __restrict__ WT, int N) {
  int idx = blockIdx.x * 256 + threadIdx.x;
  if (idx < 128 * N) {
    int col = idx >> 7;
    int k = idx & 127;
    WT[idx] = (ushort)bfr(W[(size_t)k * N + col]);
  }
}

// ---- shared GEMM epilogue: thread owns row=row0+w*16+l15, chans f*16+lhi*4+{0..3} ----
template <int N, bool OUTF8>
__device__ inline void gemm_store(float4v* acc, int row, int lhi,
                                  float dn, void* Cv, int M) {
  if (row >= M) return;
  constexpr int NF = N / 16;
#pragma unroll
  for (int f = 0; f < NF; ++f) {
    float v0 = acc[f][0] * dn, v1 = acc[f][1] * dn;
    float v2 = acc[f][2] * dn, v3 = acc[f][3] * dn;
    int ch = f * 16 + lhi * 4;
    if (OUTF8) {
      uint pk = f8pk_enc<false>(v0, v1, 0u);
      pk = f8pk_enc<true>(v2, v3, pk);
      *(uint*)((uchar*)Cv + (size_t)row * N + ch) = pk;
    } else {
      uint2 st;
      st.x = pk_bf16(v0, v1);
      st.y = pk_bf16(v2, v3);
      *(uint2*)((ushort*)Cv + (size_t)row * N + ch) = st;
    }
  }
}

// ---------------- MFMA GEMM (layer 1): C = (X@W)*dinv; swapped-operand epilogue ----------------
template <int N, bool INBF, bool OUTF8>
__global__ __launch_bounds__(256) void gemm_mfma_kernel(const void* __restrict__ Xv,
                                                        const ushort* __restrict__ WT,
                                                        const float* __restrict__ dinv,
                                                        void* __restrict__ C, int M) {
  constexpr int K = 128;
  constexpr int LDK = K + 8;
  __shared__ ushort Xs[64 * LDK];
  __shared__ ushort Ws[N * LDK];
  int tid = threadIdx.x;
  int row0 = blockIdx.x * 64;

#pragma unroll
  for (int i = 0; i < 4; ++i) {
    int idx = (tid + i * 256) * 8;
    int r = idx >> 7, c = idx & 127;
    uint4 v = make_uint4(0, 0, 0, 0);
    if (row0 + r < M) {
      if (INBF) {
        v = *(const uint4*)((const ushort*)Xv + (size_t)(row0 + r) * K + c);
      } else {
        const float* Xf = (const float*)Xv + (size_t)(row0 + r) * K + c;
        float4 f0 = *(const float4*)Xf;
        float4 f1 = *(const float4*)(Xf + 4);
        v.x = pk_bf16(f0.x, f0.y); v.y = pk_bf16(f0.z, f0.w);
        v.z = pk_bf16(f1.x, f1.y); v.w = pk_bf16(f1.z, f1.w);
      }
    }
    *(uint4*)&Xs[r * LDK + c] = v;
  }
#pragma unroll
  for (int i = 0; i < N * K / 2048; ++i) {
    int idx = (tid + i * 256) * 8;
    int col = idx >> 7, k = idx & 127;
    *(uint4*)&Ws[col * LDK + k] = *(const uint4*)&WT[col * K + k];
  }
  __syncthreads();

  int w = tid >> 6, lane = tid & 63;
  int l15 = lane & 15, lhi = lane >> 4;
  constexpr int NF = N / 16;
  float4v acc[NF];
#pragma unroll
  for (int f = 0; f < NF; ++f) acc[f] = (float4v)(0.f);

  const ushort* xbase = &Xs[(w * 16 + l15) * LDK + lhi * 8];
#pragma unroll
  for (int s = 0; s < 4; ++s) {
    short8v xa = *(const short8v*)(xbase + s * 32);
#pragma unroll
    for (int f = 0; f < NF; ++f) {
      short8v wb = *(const short8v*)&Ws[(f * 16 + l15) * LDK + s * 32 + lhi * 8];
      // swapped: D = W_frag x X_frag  =>  D[col=l15 -> row m][reg j -> channel]
      acc[f] = __builtin_amdgcn_mfma_f32_16x16x32_bf16(wb, xa, acc[f], 0, 0, 0);
    }
  }

  int row = row0 + w * 16 + l15;
  float dn = (row < M) ? dinv[row] : 0.f;
  gemm_store<N, OUTF8>(acc, row, lhi, dn, C, M);
}

// ---- XCD-partitioned partial aggregation over fp8 features (128 ch) ----
__global__ __launch_bounds__(256) void aggp_f8_kernel(const uint4* __restrict__ Tq,
                                                      const int* __restrict__ rcp,
                                                      const int* __restrict__ csr_src,
                                                      ushort* __restrict__ P, int n) {
  int c = blockIdx.x & 7;
  int g = blockIdx.x >> 3;
  constexpr int SPB = 32;
  int lane = threadIdx.x & 7;
  int slot = threadIdx.x >> 3;
  uint4* Pq = (uint4*)P + (size_t)c * n * 16;  // bf16 partial row = 16 uint4
  const int* rcp_c = rcp + (size_t)c * NN;
  for (int it = 0; it < (NPB + SPB - 1) / SPB; ++it) {
    int off = it * SPB + slot;
    if (off >= NPB) break;
    int node = g * NPB + off;
    if (node >= n) break;
    int v = rcp_c[node];
    int lo = v >> 8, hi = lo + (v & 255);
    float a[16];
#pragma unroll
    for (int j = 0; j < 16; ++j) a[j] = 0.f;
    if (chunk8(node) == c) addq_f8(Tq[(size_t)node * 8 + lane], a);
    int e = lo;
    for (; e + 4 <= hi; e += 4) {
      int s0 = csr_src[e], s1 = csr_src[e + 1];
      int s2 = csr_src[e + 2], s3 = csr_src[e + 3];
      uint4 q0 = Tq[(size_t)s0 * 8 + lane];
      uint4 q1 = Tq[(size_t)s1 * 8 + lane];
      uint4 q2 = Tq[(size_t)s2 * 8 + lane];
      uint4 q3 = Tq[(size_t)s3 * 8 + lane];
      addq_f8(q0, a); addq_f8(q1, a); addq_f8(q2, a); addq_f8(q3, a);
    }
    for (; e < hi; ++e) addq_f8(Tq[(size_t)csr_src[e] * 8 + lane], a);
    uint4 st0, st1;
    st0.x = pk_bf16(a[0], a[1]);  st0.y = pk_bf16(a[2], a[3]);
    st0.z = pk_bf16(a[4], a[5]);  st0.w = pk_bf16(a[6], a[7]);
    st1.x = pk_bf16(a[8], a[9]);  st1.y = pk_bf16(a[10], a[11]);
    st1.z = pk_bf16(a[12], a[13]); st1.w = pk_bf16(a[14], a[15]);
    ntstore4(&Pq[(size_t)node * 16 + lane * 2], st0);
    ntstore4(&Pq[(size_t)node * 16 + lane * 2 + 1], st1);
  }
}

// ---- XCD-partitioned partial aggregation over bf16 features (layer 3, 64 ch) ----
__global__ __launch_bounds__(256) void aggp_bf16_kernel(const uint4* __restrict__ Tq,
                                                        const int* __restrict__ rcp,
                                                        const int* __restrict__ csr_src,
                                                        ushort* __restrict__ P, int n) {
  int c = blockIdx.x & 7;
  int g = blockIdx.x >> 3;
  constexpr int LPN = 8, SPB = 32;
  int lane = threadIdx.x & 7;
  int slot = threadIdx.x >> 3;
  uint4* Pq = (uint4*)P + (size_t)c * n * LPN;
  const int* rcp_c = rcp + (size_t)c * NN;
  for (int it = 0; it < (NPB + SPB - 1) / SPB; ++it) {
    int off = it * SPB + slot;
    if (off >= NPB) break;
    int node = g * NPB + off;
    if (node >= n) break;
    int v = rcp_c[node];
    int lo = v >> 8, hi = lo + (v & 255);
    float a[8];
#pragma unroll
    for (int j = 0; j < 8; ++j) a[j] = 0.f;
    if (chunk8(node) == c) addq(Tq[(size_t)node * LPN + lane], a);
    int e = lo;
    for (; e + 4 <= hi; e += 4) {
      int s0 = csr_src[e], s1 = csr_src[e + 1];
      int s2 = csr_src[e + 2], s3 = csr_src[e + 3];
      uint4 q0 = Tq[(size_t)s0 * LPN + lane];
      uint4 q1 = Tq[(size_t)s1 * LPN + lane];
      uint4 q2 = Tq[(size_t)s2 * LPN + lane];
      uint4 q3 = Tq[(size_t)s3 * LPN + lane];
      addq(q0, a); addq(q1, a); addq(q2, a); addq(q3, a);
    }
    for (; e < hi; ++e) addq(Tq[(size_t)csr_src[e] * LPN + lane], a);
    uint4 st;
    st.x = pk_bf16(a[0], a[1]);
    st.y = pk_bf16(a[2], a[3]);
    st.z = pk_bf16(a[4], a[5]);
    st.w = pk_bf16(a[6], a[7]);
    ntstore4(&Pq[(size_t)node * LPN + lane], st);
  }
}

// ---- fused GEMM: h = relu(dn*sum_c P_c + b); C = (h @ W)*dinv ----
template <int N, bool OUTF8>
__global__ __launch_bounds__(256) void gemm_fused_kernel(const ushort* __restrict__ P,
                                                         const ushort* __restrict__ WT,
                                                         const float* __restrict__ dinv,
                                                         const float* __restrict__ bias,
                                                         void* __restrict__ C, int M) {
  constexpr int K = 128;
  constexpr int LDK = K + 8;
  __shared__ ushort Xs[64 * LDK];
  __shared__ ushort Ws[N * LDK];
  int tid = threadIdx.x;
  int row0 = blockIdx.x * 64;
  const uint4* Pq = (const uint4*)P;
  size_t ps = (size_t)M * 16;

  {
    int l = tid & 15;
    int rb = tid >> 4;
    float4 bv0 = *(const float4*)&bias[l * 8];
    float4 bv1 = *(const float4*)&bias[l * 8 + 4];
    float bb[8] = {bv0.x, bv0.y, bv0.z, bv0.w, bv1.x, bv1.y, bv1.z, bv1.w};
#pragma unroll
    for (int i = 0; i < 4; ++i) {
      int r = rb + i * 16;
      int row = row0 + r;
      uint4 st = make_uint4(0, 0, 0, 0);
      if (row < M) {
        float a[8];
#pragma unroll
        for (int j = 0; j < 8; ++j) a[j] = 0.f;
#pragma unroll
        for (int c = 0; c < 8; ++c)
          addq(ntload4(&Pq[(size_t)c * ps + (size_t)row * 16 + l]), a);
        float dn = dinv[row];
        float h[8];
#pragma unroll
        for (int j = 0; j < 8; ++j) h[j] = fmaxf(fmaf(dn, a[j], bb[j]), 0.f);
        st.x = pk_bf16(h[0], h[1]);
        st.y = pk_bf16(h[2], h[3]);
        st.z = pk_bf16(h[4], h[5]);
        st.w = pk_bf16(h[6], h[7]);
      }
      *(uint4*)&Xs[r * LDK + l * 8] = st;
    }
  }
#pragma unroll
  for (int i = 0; i < N * K / 2048; ++i) {
    int idx = (tid + i * 256) * 8;
    int col = idx >> 7, k = idx & 127;
    *(uint4*)&Ws[col * LDK + k] = *(const uint4*)&WT[col * K + k];
  }
  __syncthreads();

  int w = tid >> 6, lane = tid & 63;
  int l15 = lane & 15, lhi = lane >> 4;
  constexpr int NF = N / 16;
  float4v acc[NF];
#pragma unroll
  for (int f = 0; f < NF; ++f) acc[f] = (float4v)(0.f);

  const ushort* xbase = &Xs[(w * 16 + l15) * LDK + lhi * 8];
#pragma unroll
  for (int s = 0; s < 4; ++s) {
    short8v xa = *(const short8v*)(xbase + s * 32);
#pragma unroll
    for (int f = 0; f < NF; ++f) {
      short8v wb = *(const short8v*)&Ws[(f * 16 + l15) * LDK + s * 32 + lhi * 8];
      acc[f] = __builtin_amdgcn_mfma_f32_16x16x32_bf16(wb, xa, acc[f], 0, 0, 0);
    }
  }

  int row = row0 + w * 16 + l15;
  float dn = (row < M) ? dinv[row] : 0.f;
  gemm_store<N, OUTF8>(acc, row, lhi, dn, C, M);
}

// ---- layer-3 reduce: h3 = dn*sum_c P3_c + b3 -> hemb fp32; out = h3@Wout + bout ----
__global__ __launch_bounds__(256) void reduce3_kernel(const ushort* __restrict__ P,
                                                      const float* __restrict__ dinv,
                                                      const float* __restrict__ b3,
                                                      const float* __restrict__ Wout,
                                                      const float* __restrict__ bout,
                                                      float* __restrict__ Hemb,
                                                      float* __restrict__ Out, int n) {
  int t = blockIdx.x * 256 + threadIdx.x;
  int node = t >> 3;
  int lane = t & 7;
  if (node >= n) return;
  const uint4* Pq = (const uint4*)P;
  size_t ps = (size_t)n * 8;
  float a[8];
#pragma unroll
  for (int j = 0; j < 8; ++j) a[j] = 0.f;
#pragma unroll
  for (int c = 0; c < 8; ++c) addq(ntload4(&Pq[(size_t)c * ps + (size_t)node * 8 + lane]), a);
  float dn = dinv[node];
  float4 bv0 = *(const float4*)&b3[lane * 8];
  float4 bv1 = *(const float4*)&b3[lane * 8 + 4];
  float bb[8] = {bv0.x, bv0.y, bv0.z, bv0.w, bv1.x, bv1.y, bv1.z, bv1.w};
  float h[8];
#pragma unroll
  for (int j = 0; j < 8; ++j) h[j] = fmaf(dn, a[j], bb[j]);
  float* Hrow = &Hemb[(size_t)node * 64 + lane * 8];
  *(float4*)&Hrow[0] = make_float4(h[0], h[1], h[2], h[3]);
  *(float4*)&Hrow[4] = make_float4(h[4], h[5], h[6], h[7]);
  int k0 = 8 * lane;
  float p0 = 0.f, p1 = 0.f;
#pragma unroll
  for (int j = 0; j < 8; ++j) {
    p0 = fmaf(h[j], Wout[(k0 + j) * 2 + 0], p0);
    p1 = fmaf(h[j], Wout[(k0 + j) * 2 + 1], p1);
  }
#pragma unroll
  for (int off = 4; off >= 1; off >>= 1) {
    p0 += __shfl_xor(p0, off, 8);
    p1 += __shfl_xor(p1, off, 8);
  }
  if (lane == 0) {
    Out[(size_t)node * 2 + 0] = p0 + bout[0];
    Out[(size_t)node * 2 + 1] = p1 + bout[1];
  }
}

// ---- fallback (small ws): direct bf16 gather agg over rcp[c][node] segments ----
__global__ __launch_bounds__(256) void agg_fb128_kernel(const uint4* __restrict__ Tq,
                                                        const int* __restrict__ rcp,
                                                        const int* __restrict__ csr_src,
                                                        const float* __restrict__ dinv,
                                                        const float* __restrict__ bias,
                                                        ushort* __restrict__ H, int n) {
  int t = blockIdx.x * 256 + threadIdx.x;
  int node = t >> 4;
  int lane = t & 15;
  if (node >= n) return;
  float dn = dinv[node];
  float a0[8], a1[8], a2[8], a3[8];
#pragma unroll
  for (int c = 0; c < 8; ++c) { a0[c] = 0.f; a1[c] = 0.f; a2[c] = 0.f; a3[c] = 0.f; }
  addq(Tq[(size_t)node * 16 + lane], a0);
#pragma unroll
  for (int c = 0; c < 8; ++c) {
    int v = rcp[(size_t)c * NN + node];
    int lo = v >> 8, hi = lo + (v & 255);
    int e = lo;
    for (; e + 4 <= hi; e += 4) {
      uint4 q0 = Tq[(size_t)csr_src[e] * 16 + lane];
      uint4 q1 = Tq[(size_t)csr_src[e + 1] * 16 + lane];
      uint4 q2 = Tq[(size_t)csr_src[e + 2] * 16 + lane];
      uint4 q3 = Tq[(size_t)csr_src[e + 3] * 16 + lane];
      addq(q0, a0); addq(q1, a1); addq(q2, a2); addq(q3, a3);
    }
    for (; e < hi; ++e) addq(Tq[(size_t)csr_src[e] * 16 + lane], a0);
  }
  float4 bv0 = *(const float4*)&bias[lane * 8];
  float4 bv1 = *(const float4*)&bias[lane * 8 + 4];
  float bb[8] = {bv0.x, bv0.y, bv0.z, bv0.w, bv1.x, bv1.y, bv1.z, bv1.w};
  float h[8];
#pragma unroll
  for (int c = 0; c < 8; ++c) {
    h[c] = fmaf(dn, (a0[c] + a1[c]) + (a2[c] + a3[c]), bb[c]);
    h[c] = fmaxf(h[c], 0.f);
  }
  uint4 st;
  st.x = pk_bf16(h[0], h[1]);
  st.y = pk_bf16(h[2], h[3]);
  st.z = pk_bf16(h[4], h[5]);
  st.w = pk_bf16(h[6], h[7]);
  *(uint4*)&H[(size_t)node * 128 + lane * 8] = st;
}

__global__ __launch_bounds__(256) void agg_fb64_kernel(const uint4* __restrict__ Tq,
                                                       const int* __restrict__ rcp,
                                                       const int* __restrict__ csr_src,
                                                       const float* __restrict__ dinv,
                                                       const float* __restrict__ bias,
                                                       float* __restrict__ H,
                                                       const float* __restrict__ Wout,
                                                       const float* __restrict__ bout,
                                                       float* __restrict__ Out, int n) {
  int t = blockIdx.x * 256 + threadIdx.x;
  int node = t >> 3;
  int lane = t & 7;
  if (node >= n) return;
  float dn = dinv[node];
  float a0[8], a1[8], a2[8], a3[8];
#pragma unroll
  for (int c = 0; c < 8; ++c) { a0[c] = 0.f; a1[c] = 0.f; a2[c] = 0.f; a3[c] = 0.f; }
  addq(Tq[(size_t)node * 8 + lane], a0);
#pragma unroll
  for (int c = 0; c < 8; ++c) {
    int v = rcp[(size_t)c * NN + node];
    int lo = v >> 8, hi = lo + (v & 255);
    int e = lo;
    for (; e + 4 <= hi; e += 4) {
      uint4 q0 = Tq[(size_t)csr_src[e] * 8 + lane];
      uint4 q1 = Tq[(size_t)csr_src[e + 1] * 8 + lane];
      uint4 q2 = Tq[(size_t)csr_src[e + 2] * 8 + lane];
      uint4 q3 = Tq[(size_t)csr_src[e + 3] * 8 + lane];
      addq(q0, a0); addq(q1, a1); addq(q2, a2); addq(q3, a3);
    }
    for (; e < hi; ++e) addq(Tq[(size_t)csr_src[e] * 8 + lane], a0);
  }
  float4 bv0 = *(const float4*)&bias[lane * 8];
  float4 bv1 = *(const float4*)&bias[lane * 8 + 4];
  float bb[8] = {bv0.x, bv0.y, bv0.z, bv0.w, bv1.x, bv1.y, bv1.z, bv1.w};
  float h[8];
#pragma unroll
  for (int c = 0; c < 8; ++c)
    h[c] = fmaf(dn, (a0[c] + a1[c]) + (a2[c] + a3[c]), bb[c]);
  float* Hrow = &H[(size_t)node * 64 + lane * 8];
  *(float4*)&Hrow[0] = make_float4(h[0], h[1], h[2], h[3]);
  *(float4*)&Hrow[4] = make_float4(h[4], h[5], h[6], h[7]);
  int k0 = 8 * lane;
  float p0 = 0.f, p1 = 0.f;
#pragma unroll
  for (int c = 0; c < 8; ++c) {
    p0 = fmaf(h[c], Wout[(k0 + c) * 2 + 0], p0);
    p1 = fmaf(h[c], Wout[(k0 + c) * 2 + 1], p1);
  }
#pragma unroll
  for (int off = 4; off >= 1; off >>= 1) {
    p0 += __shfl_xor(p0, off, 8);
    p1 += __shfl_xor(p1, off, 8);
  }
  if (lane == 0) {
    Out[(size_t)node * 2 + 0] = p0 + bout[0];
    Out[(size_t)node * 2 + 1] = p1 + bout[1];
  }
}

extern "C" void kernel_launch(void* const* d_in, const int* in_sizes, int n_in,
                              void* d_out, int out_size, void* d_ws, size_t ws_size,
                              hipStream_t stream) {
  const float* x    = (const float*)d_in[0];
  const int*   ei   = (const int*)d_in[1];
  const float* W1   = (const float*)d_in[2];
  const float* b1   = (const float*)d_in[3];
  const float* W2   = (const float*)d_in[4];
  const float* b2   = (const float*)d_in[5];
  const float* W3   = (const float*)d_in[6];
  const float* b3   = (const float*)d_in[7];
  const float* Wout = (const float*)d_in[8];
  const float* bout = (const float*)d_in[9];

  const int n = NN, E = NE;
  const int* srcp = ei;
  const int* dstp = ei + E;

  char* ws = (char*)d_ws;
  int*    cntmat  = (int*)(ws + 0);
  int*    btotal  = (int*)(ws + 1045504);
  int*    bbase   = (int*)(ws + 1049600);
  int*    offmat  = (int*)(ws + 1053696);
  float*  dinv    = (float*)(ws + 2099200);
  int*    rcp     = (int*)(ws + 2499216);      // [c][node]
  int*    csr_src = (int*)(ws + 5699216);
  ushort* WT1     = (ushort*)(ws + 18499216);
  ushort* WT2     = (ushort*)(ws + 18531984);
  ushort* WT3     = (ushort*)(ws + 18564752);
  char*   bufT    = ws + 18581136;             // Tp: fp8 [n][128] or bf16 [n][64/128]
  ushort* Pbuf    = (ushort*)(ws + 44181136);  // 8 x 25.6MB partials
  int*    store   = (int*)(ws + 44181136);     // aliases Pbuf (dead after build)

  const size_t PRIMARY_NEED = 248981136ull;
  bool primary = ws_size >= PRIMARY_NEED;

  float* outp = (float*)d_out;
  float* hemb = (float*)d_out + 2 * n;

  // ---- graph build ----
  pcount_kernel<<<NBLK, 256, 0, stream>>>(dstp, cntmat);
  rowsum_kernel<<<NB, 256, 0, stream>>>(cntmat, btotal);
  bucket_scan_kernel<<<1, 1024, 0, stream>>>(btotal, bbase);
  offsets_kernel<<<NB, 256, 0, stream>>>(cntmat, bbase, offmat);
  pscatter_kernel<<<NBLK, 256, 0, stream>>>(srcp, dstp, offmat, store);
  build_kernel<<<NB, 256, 0, stream>>>(btotal, bbase, store, rcp, dinv, csr_src);

  wconv_kernel<<<(128 * 128 + 255) / 256, 256, 0, stream>>>(W1, WT1, 128);
  wconv_kernel<<<(128 * 128 + 255) / 256, 256, 0, stream>>>(W2, WT2, 128);
  wconv_kernel<<<(128 * 64 + 255) / 256, 256, 0, stream>>>(W3, WT3, 64);

  int gemmGrid = (n + 63) / 64;

  if (primary) {
    // layer 1: Tp1 fp8 = (x@W1)*dinv ; partial agg over fp8
    gemm_mfma_kernel<128, false, true><<<gemmGrid, 256, 0, stream>>>(x, WT1, dinv, bufT, n);
    aggp_f8_kernel<<<NGRP * 8, 256, 0, stream>>>((const uint4*)bufT, rcp, csr_src, Pbuf, n);
    // layer 2: fused reduce+GEMM -> Tp2 fp8
    gemm_fused_kernel<128, true><<<gemmGrid, 256, 0, stream>>>(Pbuf, WT2, dinv, b1, bufT, n);
    aggp_f8_kernel<<<NGRP * 8, 256, 0, stream>>>((const uint4*)bufT, rcp, csr_src, Pbuf, n);
    // layer 3: fused reduce+GEMM -> Tp3 bf16 [n][64]; bf16 partial agg
    gemm_fused_kernel<64, false><<<gemmGrid, 256, 0, stream>>>(Pbuf, WT3, dinv, b2, bufT, n);
    aggp_bf16_kernel<<<NGRP * 8, 256, 0, stream>>>((const uint4*)bufT, rcp, csr_src, Pbuf, n);
    reduce3_kernel<<<(n * 8 + 255) / 256, 256, 0, stream>>>(Pbuf, dinv, b3, Wout, bout,
                                                            hemb, outp, n);
  } else {
    // fallback: bf16 everything, direct gather
    ushort* bufHb = Pbuf;
    gemm_mfma_kernel<128, false, false><<<gemmGrid, 256, 0, stream>>>(x, WT1, dinv, bufT, n);
    agg_fb128_kernel<<<(n * 16 + 255) / 256, 256, 0, stream>>>(
        (const uint4*)bufT, rcp, csr_src, dinv, b1, bufHb, n);
    gemm_mfma_kernel<128, true, false><<<gemmGrid, 256, 0, stream>>>(bufHb, WT2, dinv, bufT, n);
    agg_fb128_kernel<<<(n * 16 + 255) / 256, 256, 0, stream>>>(
        (const uint4*)bufT, rcp, csr_src, dinv, b2, bufHb, n);
    gemm_mfma_kernel<64, true, false><<<gemmGrid, 256, 0, stream>>>(bufHb, WT3, dinv, bufT, n);
    agg_fb64_kernel<<<(n * 8 + 255) / 256, 256, 0, stream>>>(
        (const uint4*)bufT, rcp, csr_src, dinv, b3, hemb, Wout, bout, outp, n);
  }
}

// Round 18
// 358.913 us; speedup vs baseline: 1.7241x; 1.2013x over previous
//
#include <hip/hip_runtime.h>

#define NN 100000
#define NE 3200000
#define NB 1021        // buckets
#define BNODES 98      // nodes per bucket (98*1021 >= NN)
#define NBLK 256       // partition blocks
#define CH 12500       // edges per partition block (NBLK*CH == NE)
#define NCHUNK 4       // src chunks of 25000 nodes; 3.2MB fp8 slice < 4MB L2/XCD
#define CNODES 25000
#define NPB 400        // nodes per group in aggp
#define NGRP 256       // groups; NGRP*NPB >= NN

typedef unsigned int uint;
typedef unsigned char uchar;
typedef __attribute__((ext_vector_type(8))) short short8v;
typedef __attribute__((ext_vector_type(4))) float float4v;
typedef __attribute__((ext_vector_type(2))) float float2v;
typedef __attribute__((ext_vector_type(4))) uint uint4v;

#if defined(__has_builtin)
#if __has_builtin(__builtin_amdgcn_cvt_pk_f32_fp8) && __has_builtin(__builtin_amdgcn_cvt_pk_fp8_f32)
#define HAVE_FP8_CVT 1
#endif
#endif

// ---- bf16 helpers ----
__device__ inline uint bfr(float f) {  // RTNE, scalar (cold paths)
  uint u = __float_as_uint(f);
  return (u + 0x7fffu + ((u >> 16) & 1u)) >> 16;
}
__device__ inline uint pk_bf16(float a, float b) {  // HW packed cvt (hot epilogues)
  uint r;
  asm("v_cvt_pk_bf16_f32 %0, %1, %2" : "=v"(r) : "v"(a), "v"(b));
  return r;
}
__device__ inline void addq(uint4 q, float* a) {  // bf16x8 unpack-add
  uint u[4] = {q.x, q.y, q.z, q.w};
#pragma unroll
  for (int j = 0; j < 4; ++j) {
    a[2 * j]     += __uint_as_float(u[j] << 16);
    a[2 * j + 1] += __uint_as_float(u[j] & 0xffff0000u);
  }
}

// ---- fp8 e4m3 helpers (HI compile-time: builtins need immediate operands) ----
#ifndef HAVE_FP8_CVT
__device__ inline float f8dec(uint b) {
  uint s = (b >> 7) & 1u, e = (b >> 3) & 15u, m = b & 7u;
  float v;
  if (e == 0) v = (float)m * 0.001953125f;
  else v = __uint_as_float(((e + 120u) << 23) | (m << 20));
  return s ? -v : v;
}
__device__ inline uint f8enc(float f) {
  uint s = __float_as_uint(f) >> 31;
  float af = fabsf(f);
  if (!(af < 448.f)) af = 448.f;
  uint out;
  if (af < 0.015625f) {
    out = (uint)__float2int_rn(af * 512.f);
  } else {
    uint au = __float_as_uint(af);
    int exp = (int)(au >> 23) - 127;
    uint m = au & 0x7fffffu;
    uint mr = (m >> 20) + (((m & 0xfffffu) > 0x80000u) || (((m & 0xfffffu) == 0x80000u) && ((m >> 20) & 1u)) ? 1u : 0u);
    uint E = (uint)(exp + 7);
    if (mr == 8) { mr = 0; E += 1; }
    if (E > 15) { E = 15; mr = 6; }
    out = (E << 3) | mr;
  }
  return out | (s << 7);
}
#endif
template <bool HI>
__device__ inline float2v f8pk(uint u) {
#ifdef HAVE_FP8_CVT
  return __builtin_amdgcn_cvt_pk_f32_fp8(u, HI);
#else
  float2v r;
  r.x = f8dec(HI ? ((u >> 16) & 255u) : (u & 255u));
  r.y = f8dec(HI ? (u >> 24) : ((u >> 8) & 255u));
  return r;
#endif
}
template <bool HI>
__device__ inline uint f8pk_enc(float a, float b, uint old) {
#ifdef HAVE_FP8_CVT
  return __builtin_amdgcn_cvt_pk_fp8_f32(a, b, old, HI);
#else
  uint two = f8enc(a) | (f8enc(b) << 8);
  return HI ? ((old & 0x0000ffffu) | (two << 16)) : ((old & 0xffff0000u) | two);
#endif
}
__device__ inline void addq_f8(uint4 q, float* a) {  // 16 fp8 -> 16 f32 adds
  uint u[4] = {q.x, q.y, q.z, q.w};
#pragma unroll
  for (int j = 0; j < 4; ++j) {
    float2v lo = f8pk<false>(u[j]);
    float2v hi = f8pk<true>(u[j]);
    a[4 * j + 0] += lo.x; a[4 * j + 1] += lo.y;
    a[4 * j + 2] += hi.x; a[4 * j + 3] += hi.y;
  }
}

// non-temporal 16B helpers
__device__ inline uint4 ntload4(const uint4* p) {
  uint4v v = __builtin_nontemporal_load((const uint4v*)p);
  return make_uint4(v.x, v.y, v.z, v.w);
}
__device__ inline void ntstore4(uint4* p, uint4 q) {
  uint4v v = {q.x, q.y, q.z, q.w};
  __builtin_nontemporal_store(v, (uint4v*)p);
}
// chunk = s / 25000 via magic multiply (exact for s < 2^17)
__device__ inline int chunk4(int s) {
  return (int)(((unsigned long long)(uint)s * 171799ull) >> 32);
}

// ---------------- P1: per-block bucket histogram ----------------
__global__ __launch_bounds__(256) void pcount_kernel(const int* __restrict__ dst,
                                                     int* __restrict__ cntmat) {
  __shared__ int cnt[NB];
  int bk = blockIdx.x, tid = threadIdx.x;
  for (int j = tid; j < NB; j += 256) cnt[j] = 0;
  __syncthreads();
  int base = bk * CH;
  for (int i = base + tid * 4; i < base + CH; i += 1024) {
    int4 d4 = *(const int4*)&dst[i];
    atomicAdd(&cnt[(uint)d4.x / (uint)BNODES], 1);
    atomicAdd(&cnt[(uint)d4.y / (uint)BNODES], 1);
    atomicAdd(&cnt[(uint)d4.z / (uint)BNODES], 1);
    atomicAdd(&cnt[(uint)d4.w / (uint)BNODES], 1);
  }
  __syncthreads();
  for (int j = tid; j < NB; j += 256) cntmat[(size_t)j * NBLK + bk] = cnt[j];
}

// ---------------- P2a: bucket totals ----------------
__global__ __launch_bounds__(256) void rowsum_kernel(const int* __restrict__ cntmat,
                                                     int* __restrict__ btotal) {
  int b = blockIdx.x, t = threadIdx.x;
  int v = cntmat[(size_t)b * NBLK + t];
#pragma unroll
  for (int off = 32; off >= 1; off >>= 1) v += __shfl_xor(v, off, 64);
  __shared__ int ws[4];
  if ((t & 63) == 0) ws[t >> 6] = v;
  __syncthreads();
  if (t == 0) btotal[b] = ws[0] + ws[1] + ws[2] + ws[3];
}

// ---------------- P2b: scan bucket totals -> bases ----------------
__global__ __launch_bounds__(1024) void bucket_scan_kernel(const int* __restrict__ btotal,
                                                           int* __restrict__ bbase) {
  __shared__ int sh[1024];
  int i = threadIdx.x;
  int v = (i < NB) ? btotal[i] : 0;
  sh[i] = v;
  __syncthreads();
  for (int off = 1; off < 1024; off <<= 1) {
    int t = (i >= off) ? sh[i - off] : 0;
    __syncthreads();
    sh[i] += t;
    __syncthreads();
  }
  if (i < NB) bbase[i] = sh[i] - v;
}

// ---------------- P2c: per-(bucket,block) offsets ----------------
__global__ __launch_bounds__(256) void offsets_kernel(const int* __restrict__ cntmat,
                                                      const int* __restrict__ bbase,
                                                      int* __restrict__ offmat) {
  __shared__ int sh[256];
  int b = blockIdx.x, t = threadIdx.x;
  int v = cntmat[(size_t)b * NBLK + t];
  sh[t] = v;
  __syncthreads();
  for (int off = 1; off < 256; off <<= 1) {
    int u = (t >= off) ? sh[t - off] : 0;
    __syncthreads();
    sh[t] += u;
    __syncthreads();
  }
  offmat[(size_t)b * NBLK + t] = bbase[b] + sh[t] - v;
}

// ---------------- P3: scatter into bucket-contiguous store (packed 4B) ----------------
__global__ __launch_bounds__(256) void pscatter_kernel(const int* __restrict__ src,
                                                       const int* __restrict__ dst,
                                                       const int* __restrict__ offmat,
                                                       int* __restrict__ store) {
  __shared__ int lcur[NB];
  int bk = blockIdx.x, tid = threadIdx.x;
  for (int j = tid; j < NB; j += 256) lcur[j] = offmat[(size_t)j * NBLK + bk];
  __syncthreads();
  int base = bk * CH;
  for (int i = base + tid * 4; i < base + CH; i += 1024) {
    int4 d4 = *(const int4*)&dst[i];
    int4 s4 = *(const int4*)&src[i];
    int dd[4] = {d4.x, d4.y, d4.z, d4.w};
    int ss[4] = {s4.x, s4.y, s4.z, s4.w};
#pragma unroll
    for (int j = 0; j < 4; ++j) {
      uint b = (uint)dd[j] / (uint)BNODES;
      int dl = dd[j] - (int)(b * BNODES);
      int pos = atomicAdd(&lcur[b], 1);
      store[pos] = ss[j] | (dl << 17);
    }
  }
}

// ---------------- P4: per-bucket chunk-major CSR + rcp[c][node] + dinv ----------------
__global__ __launch_bounds__(256) void build_kernel(const int* __restrict__ btotal,
                                                    const int* __restrict__ bbase,
                                                    const int* __restrict__ store,
                                                    int* __restrict__ rcp,
                                                    float* __restrict__ dinv,
                                                    int* __restrict__ csr_src) {
  __shared__ int cnt2[NCHUNK * BNODES];
  __shared__ int excl2[NCHUNK * BNODES];
  int b = blockIdx.x, tid = threadIdx.x;
  int nb0 = b * BNODES;
  int nn = min(BNODES, NN - nb0);
  for (int j = tid; j < NCHUNK * BNODES; j += 256) cnt2[j] = 0;
  __syncthreads();
  int sz = btotal[b], bb = bbase[b];
  const int* bs = store + bb;
  for (int e = tid; e < sz; e += 256) {
    int p = bs[e];
    int dl = (int)((uint)p >> 17);
    int s = p & 0x1FFFF;
    atomicAdd(&cnt2[chunk4(s) * BNODES + dl], 1);
  }
  __syncthreads();
  if (tid == 0) {
    int run = 0;
    for (int j = 0; j < NCHUNK * BNODES; ++j) { excl2[j] = run; run += cnt2[j]; }
  }
  __syncthreads();
  for (int j = tid; j < nn; j += 256) {
    int deg = 0;
#pragma unroll
    for (int c = 0; c < NCHUNK; ++c) {
      int bin = c * BNODES + j;
      rcp[(size_t)c * NN + nb0 + j] = ((bb + excl2[bin]) << 8) | cnt2[bin];
      deg += cnt2[bin];
    }
    dinv[nb0 + j] = rsqrtf((float)(deg + 1));
  }
  __syncthreads();
  for (int j = tid; j < NCHUNK * BNODES; j += 256) cnt2[j] = 0;  // cursors
  __syncthreads();
  for (int e = tid; e < sz; e += 256) {
    int p = bs[e];
    int dl = (int)((uint)p >> 17);
    int s = p & 0x1FFFF;
    int bin = chunk4(s) * BNODES + dl;
    int pos = atomicAdd(&cnt2[bin], 1);
    csr_src[bb + excl2[bin] + pos] = s;
  }
}

// ---------------- W -> bf16 transposed: WT[col][k] = bf16(W[k][col]), K=128 ----------------
__global__ __launch_bounds__(256) void wconv_kernel(const float* __restrict__ W,
                                                    ushort* __restrict__ WT, int N) {
  int idx = blockIdx.x * 256 + threadIdx.x;
  if (idx < 128 * N) {
    int col = idx >> 7;
    int k = idx & 127;
    WT[idx] = (ushort)bfr(W[(size_t)k * N + col]);
  }
}

// ---- shared GEMM epilogue: thread owns row=row0+w*16+l15, chans f*16+lhi*4+{0..3} ----
template <int N, bool OUTF8>
__device__ inline void gemm_store(float4v* acc, int row, int lhi,
                                  float dn, void* Cv, int M) {
  if (row >= M) return;
  constexpr int NF = N / 16;
#pragma unroll
  for (int f = 0; f < NF; ++f) {
    float v0 = acc[f][0] * dn, v1 = acc[f][1] * dn;
    float v2 = acc[f][2] * dn, v3 = acc[f][3] * dn;
    int ch = f * 16 + lhi * 4;
    if (OUTF8) {
      uint pk = f8pk_enc<false>(v0, v1, 0u);
      pk = f8pk_enc<true>(v2, v3, pk);
      *(uint*)((uchar*)Cv + (size_t)row * N + ch) = pk;
    } else {
      uint2 st;
      st.x = pk_bf16(v0, v1);
      st.y = pk_bf16(v2, v3);
      *(uint2*)((ushort*)Cv + (size_t)row * N + ch) = st;
    }
  }
}

// ---------------- MFMA GEMM (layer 1): C = (X@W)*dinv; swapped-operand epilogue ----------------
template <int N, bool INBF, bool OUTF8>
__global__ __launch_bounds__(256) void gemm_mfma_kernel(const void* __restrict__ Xv,
                                                        const ushort* __restrict__ WT,
                                                        const float* __restrict__ dinv,
                                                        void* __restrict__ C, int M) {
  constexpr int K = 128;
  constexpr int LDK = K + 8;
  __shared__ ushort Xs[64 * LDK];
  __shared__ ushort Ws[N * LDK];
  int tid = threadIdx.x;
  int row0 = blockIdx.x * 64;

#pragma unroll
  for (int i = 0; i < 4; ++i) {
    int idx = (tid + i * 256) * 8;
    int r = idx >> 7, c = idx & 127;
    uint4 v = make_uint4(0, 0, 0, 0);
    if (row0 + r < M) {
      if (INBF) {
        v = *(const uint4*)((const ushort*)Xv + (size_t)(row0 + r) * K + c);
      } else {
        const float* Xf = (const float*)Xv + (size_t)(row0 + r) * K + c;
        float4 f0 = *(const float4*)Xf;
        float4 f1 = *(const float4*)(Xf + 4);
        v.x = pk_bf16(f0.x, f0.y); v.y = pk_bf16(f0.z, f0.w);
        v.z = pk_bf16(f1.x, f1.y); v.w = pk_bf16(f1.z, f1.w);
      }
    }
    *(uint4*)&Xs[r * LDK + c] = v;
  }
#pragma unroll
  for (int i = 0; i < N * K / 2048; ++i) {
    int idx = (tid + i * 256) * 8;
    int col = idx >> 7, k = idx & 127;
    *(uint4*)&Ws[col * LDK + k] = *(const uint4*)&WT[col * K + k];
  }
  __syncthreads();

  int w = tid >> 6, lane = tid & 63;
  int l15 = lane & 15, lhi = lane >> 4;
  constexpr int NF = N / 16;
  float4v acc[NF];
#pragma unroll
  for (int f = 0; f < NF; ++f) acc[f] = (float4v)(0.f);

  const ushort* xbase = &Xs[(w * 16 + l15) * LDK + lhi * 8];
#pragma unroll
  for (int s = 0; s < 4; ++s) {
    short8v xa = *(const short8v*)(xbase + s * 32);
#pragma unroll
    for (int f = 0; f < NF; ++f) {
      short8v wb = *(const short8v*)&Ws[(f * 16 + l15) * LDK + s * 32 + lhi * 8];
      acc[f] = __builtin_amdgcn_mfma_f32_16x16x32_bf16(wb, xa, acc[f], 0, 0, 0);
    }
  }

  int row = row0 + w * 16 + l15;
  float dn = (row < M) ? dinv[row] : 0.f;
  gemm_store<N, OUTF8>(acc, row, lhi, dn, C, M);
}

// ---- XCD-partitioned partial aggregation over fp8 features (128 ch) ----
// chunk = blockIdx&3; XCDs c and c+4 cache the same 3.2MB slice.
__global__ __launch_bounds__(256) void aggp_f8_kernel(const uint4* __restrict__ Tq,
                                                      const int* __restrict__ rcp,
                                                      const int* __restrict__ csr_src,
                                                      ushort* __restrict__ P, int n) {
  int c = blockIdx.x & 3;
  int g = blockIdx.x >> 2;
  constexpr int SPB = 32;
  int lane = threadIdx.x & 7;
  int slot = threadIdx.x >> 3;
  uint4* Pq = (uint4*)P + (size_t)c * n * 16;  // bf16 partial row = 16 uint4
  const int* rcp_c = rcp + (size_t)c * NN;
  for (int it = 0; it < (NPB + SPB - 1) / SPB; ++it) {
    int off = it * SPB + slot;
    if (off >= NPB) break;
    int node = g * NPB + off;
    if (node >= n) break;
    int v = rcp_c[node];
    int lo = v >> 8, hi = lo + (v & 255);
    float a[16];
#pragma unroll
    for (int j = 0; j < 16; ++j) a[j] = 0.f;
    if (chunk4(node) == c) addq_f8(Tq[(size_t)node * 8 + lane], a);
    int e = lo;
    for (; e + 4 <= hi; e += 4) {
      int s0 = csr_src[e], s1 = csr_src[e + 1];
      int s2 = csr_src[e + 2], s3 = csr_src[e + 3];
      uint4 q0 = Tq[(size_t)s0 * 8 + lane];
      uint4 q1 = Tq[(size_t)s1 * 8 + lane];
      uint4 q2 = Tq[(size_t)s2 * 8 + lane];
      uint4 q3 = Tq[(size_t)s3 * 8 + lane];
      addq_f8(q0, a); addq_f8(q1, a); addq_f8(q2, a); addq_f8(q3, a);
    }
    for (; e < hi; ++e) addq_f8(Tq[(size_t)csr_src[e] * 8 + lane], a);
    uint4 st0, st1;
    st0.x = pk_bf16(a[0], a[1]);  st0.y = pk_bf16(a[2], a[3]);
    st0.z = pk_bf16(a[4], a[5]);  st0.w = pk_bf16(a[6], a[7]);
    st1.x = pk_bf16(a[8], a[9]);  st1.y = pk_bf16(a[10], a[11]);
    st1.z = pk_bf16(a[12], a[13]); st1.w = pk_bf16(a[14], a[15]);
    ntstore4(&Pq[(size_t)node * 16 + lane * 2], st0);
    ntstore4(&Pq[(size_t)node * 16 + lane * 2 + 1], st1);
  }
}

// ---- XCD-partitioned partial aggregation over bf16 features (layer 3, 64 ch) ----
__global__ __launch_bounds__(256) void aggp_bf16_kernel(const uint4* __restrict__ Tq,
                                                        const int* __restrict__ rcp,
                                                        const int* __restrict__ csr_src,
                                                        ushort* __restrict__ P, int n) {
  int c = blockIdx.x & 3;
  int g = blockIdx.x >> 2;
  constexpr int LPN = 8, SPB = 32;
  int lane = threadIdx.x & 7;
  int slot = threadIdx.x >> 3;
  uint4* Pq = (uint4*)P + (size_t)c * n * LPN;
  const int* rcp_c = rcp + (size_t)c * NN;
  for (int it = 0; it < (NPB + SPB - 1) / SPB; ++it) {
    int off = it * SPB + slot;
    if (off >= NPB) break;
    int node = g * NPB + off;
    if (node >= n) break;
    int v = rcp_c[node];
    int lo = v >> 8, hi = lo + (v & 255);
    float a[8];
#pragma unroll
    for (int j = 0; j < 8; ++j) a[j] = 0.f;
    if (chunk4(node) == c) addq(Tq[(size_t)node * LPN + lane], a);
    int e = lo;
    for (; e + 4 <= hi; e += 4) {
      int s0 = csr_src[e], s1 = csr_src[e + 1];
      int s2 = csr_src[e + 2], s3 = csr_src[e + 3];
      uint4 q0 = Tq[(size_t)s0 * LPN + lane];
      uint4 q1 = Tq[(size_t)s1 * LPN + lane];
      uint4 q2 = Tq[(size_t)s2 * LPN + lane];
      uint4 q3 = Tq[(size_t)s3 * LPN + lane];
      addq(q0, a); addq(q1, a); addq(q2, a); addq(q3, a);
    }
    for (; e < hi; ++e) addq(Tq[(size_t)csr_src[e] * LPN + lane], a);
    uint4 st;
    st.x = pk_bf16(a[0], a[1]);
    st.y = pk_bf16(a[2], a[3]);
    st.z = pk_bf16(a[4], a[5]);
    st.w = pk_bf16(a[6], a[7]);
    ntstore4(&Pq[(size_t)node * LPN + lane], st);
  }
}

// ---- fused GEMM: h = relu(dn*sum_c P_c + b); C = (h @ W)*dinv ----
template <int N, bool OUTF8>
__global__ __launch_bounds__(256) void gemm_fused_kernel(const ushort* __restrict__ P,
                                                         const ushort* __restrict__ WT,
                                                         const float* __restrict__ dinv,
                                                         const float* __restrict__ bias,
                                                         void* __restrict__ C, int M) {
  constexpr int K = 128;
  constexpr int LDK = K + 8;
  __shared__ ushort Xs[64 * LDK];
  __shared__ ushort Ws[N * LDK];
  int tid = threadIdx.x;
  int row0 = blockIdx.x * 64;
  const uint4* Pq = (const uint4*)P;
  size_t ps = (size_t)M * 16;

  {
    int l = tid & 15;
    int rb = tid >> 4;
    float4 bv0 = *(const float4*)&bias[l * 8];
    float4 bv1 = *(const float4*)&bias[l * 8 + 4];
    float bb[8] = {bv0.x, bv0.y, bv0.z, bv0.w, bv1.x, bv1.y, bv1.z, bv1.w};
#pragma unroll
    for (int i = 0; i < 4; ++i) {
      int r = rb + i * 16;
      int row = row0 + r;
      uint4 st = make_uint4(0, 0, 0, 0);
      if (row < M) {
        float a[8];
#pragma unroll
        for (int j = 0; j < 8; ++j) a[j] = 0.f;
#pragma unroll
        for (int c = 0; c < NCHUNK; ++c)
          addq(ntload4(&Pq[(size_t)c * ps + (size_t)row * 16 + l]), a);
        float dn = dinv[row];
        float h[8];
#pragma unroll
        for (int j = 0; j < 8; ++j) h[j] = fmaxf(fmaf(dn, a[j], bb[j]), 0.f);
        st.x = pk_bf16(h[0], h[1]);
        st.y = pk_bf16(h[2], h[3]);
        st.z = pk_bf16(h[4], h[5]);
        st.w = pk_bf16(h[6], h[7]);
      }
      *(uint4*)&Xs[r * LDK + l * 8] = st;
    }
  }
#pragma unroll
  for (int i = 0; i < N * K / 2048; ++i) {
    int idx = (tid + i * 256) * 8;
    int col = idx >> 7, k = idx & 127;
    *(uint4*)&Ws[col * LDK + k] = *(const uint4*)&WT[col * K + k];
  }
  __syncthreads();

  int w = tid >> 6, lane = tid & 63;
  int l15 = lane & 15, lhi = lane >> 4;
  constexpr int NF = N / 16;
  float4v acc[NF];
#pragma unroll
  for (int f = 0; f < NF; ++f) acc[f] = (float4v)(0.f);

  const ushort* xbase = &Xs[(w * 16 + l15) * LDK + lhi * 8];
#pragma unroll
  for (int s = 0; s < 4; ++s) {
    short8v xa = *(const short8v*)(xbase + s * 32);
#pragma unroll
    for (int f = 0; f < NF; ++f) {
      short8v wb = *(const short8v*)&Ws[(f * 16 + l15) * LDK + s * 32 + lhi * 8];
      acc[f] = __builtin_amdgcn_mfma_f32_16x16x32_bf16(wb, xa, acc[f], 0, 0, 0);
    }
  }

  int row = row0 + w * 16 + l15;
  float dn = (row < M) ? dinv[row] : 0.f;
  gemm_store<N, OUTF8>(acc, row, lhi, dn, C, M);
}

// ---- layer-3 reduce: h3 = dn*sum_c P3_c + b3 -> hemb fp32; out = h3@Wout + bout ----
__global__ __launch_bounds__(256) void reduce3_kernel(const ushort* __restrict__ P,
                                                      const float* __restrict__ dinv,
                                                      const float* __restrict__ b3,
                                                      const float* __restrict__ Wout,
                                                      const float* __restrict__ bout,
                                                      float* __restrict__ Hemb,
                                                      float* __restrict__ Out, int n) {
  int t = blockIdx.x * 256 + threadIdx.x;
  int node = t >> 3;
  int lane = t & 7;
  if (node >= n) return;
  const uint4* Pq = (const uint4*)P;
  size_t ps = (size_t)n * 8;
  float a[8];
#pragma unroll
  for (int j = 0; j < 8; ++j) a[j] = 0.f;
#pragma unroll
  for (int c = 0; c < NCHUNK; ++c) addq(ntload4(&Pq[(size_t)c * ps + (size_t)node * 8 + lane]), a);
  float dn = dinv[node];
  float4 bv0 = *(const float4*)&b3[lane * 8];
  float4 bv1 = *(const float4*)&b3[lane * 8 + 4];
  float bb[8] = {bv0.x, bv0.y, bv0.z, bv0.w, bv1.x, bv1.y, bv1.z, bv1.w};
  float h[8];
#pragma unroll
  for (int j = 0; j < 8; ++j) h[j] = fmaf(dn, a[j], bb[j]);
  float* Hrow = &Hemb[(size_t)node * 64 + lane * 8];
  *(float4*)&Hrow[0] = make_float4(h[0], h[1], h[2], h[3]);
  *(float4*)&Hrow[4] = make_float4(h[4], h[5], h[6], h[7]);
  int k0 = 8 * lane;
  float p0 = 0.f, p1 = 0.f;
#pragma unroll
  for (int j = 0; j < 8; ++j) {
    p0 = fmaf(h[j], Wout[(k0 + j) * 2 + 0], p0);
    p1 = fmaf(h[j], Wout[(k0 + j) * 2 + 1], p1);
  }
#pragma unroll
  for (int off = 4; off >= 1; off >>= 1) {
    p0 += __shfl_xor(p0, off, 8);
    p1 += __shfl_xor(p1, off, 8);
  }
  if (lane == 0) {
    Out[(size_t)node * 2 + 0] = p0 + bout[0];
    Out[(size_t)node * 2 + 1] = p1 + bout[1];
  }
}

// ---- fallback (small ws): direct bf16 gather agg over rcp[c][node] segments ----
__global__ __launch_bounds__(256) void agg_fb128_kernel(const uint4* __restrict__ Tq,
                                                        const int* __restrict__ rcp,
                                                        const int* __restrict__ csr_src,
                                                        const float* __restrict__ dinv,
                                                        const float* __restrict__ bias,
                                                        ushort* __restrict__ H, int n) {
  int t = blockIdx.x * 256 + threadIdx.x;
  int node = t >> 4;
  int lane = t & 15;
  if (node >= n) return;
  float dn = dinv[node];
  float a0[8], a1[8], a2[8], a3[8];
#pragma unroll
  for (int c = 0; c < 8; ++c) { a0[c] = 0.f; a1[c] = 0.f; a2[c] = 0.f; a3[c] = 0.f; }
  addq(Tq[(size_t)node * 16 + lane], a0);
#pragma unroll
  for (int c = 0; c < NCHUNK; ++c) {
    int v = rcp[(size_t)c * NN + node];
    int lo = v >> 8, hi = lo + (v & 255);
    int e = lo;
    for (; e + 4 <= hi; e += 4) {
      uint4 q0 = Tq[(size_t)csr_src[e] * 16 + lane];
      uint4 q1 = Tq[(size_t)csr_src[e + 1] * 16 + lane];
      uint4 q2 = Tq[(size_t)csr_src[e + 2] * 16 + lane];
      uint4 q3 = Tq[(size_t)csr_src[e + 3] * 16 + lane];
      addq(q0, a0); addq(q1, a1); addq(q2, a2); addq(q3, a3);
    }
    for (; e < hi; ++e) addq(Tq[(size_t)csr_src[e] * 16 + lane], a0);
  }
  float4 bv0 = *(const float4*)&bias[lane * 8];
  float4 bv1 = *(const float4*)&bias[lane * 8 + 4];
  float bb[8] = {bv0.x, bv0.y, bv0.z, bv0.w, bv1.x, bv1.y, bv1.z, bv1.w};
  float h[8];
#pragma unroll
  for (int c = 0; c < 8; ++c) {
    h[c] = fmaf(dn, (a0[c] + a1[c]) + (a2[c] + a3[c]), bb[c]);
    h[c] = fmaxf(h[c], 0.f);
  }
  uint4 st;
  st.x = pk_bf16(h[0], h[1]);
  st.y = pk_bf16(h[2], h[3]);
  st.z = pk_bf16(h[4], h[5]);
  st.w = pk_bf16(h[6], h[7]);
  *(uint4*)&H[(size_t)node * 128 + lane * 8] = st;
}

__global__ __launch_bounds__(256) void agg_fb64_kernel(const uint4* __restrict__ Tq,
                                                       const int* __restrict__ rcp,
                                                       const int* __restrict__ csr_src,
                                                       const float* __restrict__ dinv,
                                                       const float* __restrict__ bias,
                                                       float* __restrict__ H,
                                                       const float* __restrict__ Wout,
                                                       const float* __restrict__ bout,
                                                       float* __restrict__ Out, int n) {
  int t = blockIdx.x * 256 + threadIdx.x;
  int node = t >> 3;
  int lane = t & 7;
  if (node >= n) return;
  float dn = dinv[node];
  float a0[8], a1[8], a2[8], a3[8];
#pragma unroll
  for (int c = 0; c < 8; ++c) { a0[c] = 0.f; a1[c] = 0.f; a2[c] = 0.f; a3[c] = 0.f; }
  addq(Tq[(size_t)node * 8 + lane], a0);
#pragma unroll
  for (int c = 0; c < NCHUNK; ++c) {
    int v = rcp[(size_t)c * NN + node];
    int lo = v >> 8, hi = lo + (v & 255);
    int e = lo;
    for (; e + 4 <= hi; e += 4) {
      uint4 q0 = Tq[(size_t)csr_src[e] * 8 + lane];
      uint4 q1 = Tq[(size_t)csr_src[e + 1] * 8 + lane];
      uint4 q2 = Tq[(size_t)csr_src[e + 2] * 8 + lane];
      uint4 q3 = Tq[(size_t)csr_src[e + 3] * 8 + lane];
      addq(q0, a0); addq(q1, a1); addq(q2, a2); addq(q3, a3);
    }
    for (; e < hi; ++e) addq(Tq[(size_t)csr_src[e] * 8 + lane], a0);
  }
  float4 bv0 = *(const float4*)&bias[lane * 8];
  float4 bv1 = *(const float4*)&bias[lane * 8 + 4];
  float bb[8] = {bv0.x, bv0.y, bv0.z, bv0.w, bv1.x, bv1.y, bv1.z, bv1.w};
  float h[8];
#pragma unroll
  for (int c = 0; c < 8; ++c)
    h[c] = fmaf(dn, (a0[c] + a1[c]) + (a2[c] + a3[c]), bb[c]);
  float* Hrow = &H[(size_t)node * 64 + lane * 8];
  *(float4*)&Hrow[0] = make_float4(h[0], h[1], h[2], h[3]);
  *(float4*)&Hrow[4] = make_float4(h[4], h[5], h[6], h[7]);
  int k0 = 8 * lane;
  float p0 = 0.f, p1 = 0.f;
#pragma unroll
  for (int c = 0; c < 8; ++c) {
    p0 = fmaf(h[c], Wout[(k0 + c) * 2 + 0], p0);
    p1 = fmaf(h[c], Wout[(k0 + c) * 2 + 1], p1);
  }
#pragma unroll
  for (int off = 4; off >= 1; off >>= 1) {
    p0 += __shfl_xor(p0, off, 8);
    p1 += __shfl_xor(p1, off, 8);
  }
  if (lane == 0) {
    Out[(size_t)node * 2 + 0] = p0 + bout[0];
    Out[(size_t)node * 2 + 1] = p1 + bout[1];
  }
}

extern "C" void kernel_launch(void* const* d_in, const int* in_sizes, int n_in,
                              void* d_out, int out_size, void* d_ws, size_t ws_size,
                              hipStream_t stream) {
  const float* x    = (const float*)d_in[0];
  const int*   ei   = (const int*)d_in[1];
  const float* W1   = (const float*)d_in[2];
  const float* b1   = (const float*)d_in[3];
  const float* W2   = (const float*)d_in[4];
  const float* b2   = (const float*)d_in[5];
  const float* W3   = (const float*)d_in[6];
  const float* b3   = (const float*)d_in[7];
  const float* Wout = (const float*)d_in[8];
  const float* bout = (const float*)d_in[9];

  const int n = NN, E = NE;
  const int* srcp = ei;
  const int* dstp = ei + E;

  char* ws = (char*)d_ws;
  int*    cntmat  = (int*)(ws + 0);
  int*    btotal  = (int*)(ws + 1045504);
  int*    bbase   = (int*)(ws + 1049600);
  int*    offmat  = (int*)(ws + 1053696);
  float*  dinv    = (float*)(ws + 2099200);
  int*    rcp     = (int*)(ws + 2499216);      // [c][node], c<4 -> 1.6MB
  int*    csr_src = (int*)(ws + 5699216);
  ushort* WT1     = (ushort*)(ws + 18499216);
  ushort* WT2     = (ushort*)(ws + 18531984);
  ushort* WT3     = (ushort*)(ws + 18564752);
  char*   bufT    = ws + 18581136;             // Tp: fp8 [n][128] or bf16 [n][64/128]
  ushort* Pbuf    = (ushort*)(ws + 44181136);  // 4 x 25.6MB partials -> 146,581,136
  int*    store   = (int*)(ws + 44181136);     // aliases Pbuf (dead after build)

  const size_t PRIMARY_NEED = 146581136ull;
  bool primary = ws_size >= PRIMARY_NEED;

  float* outp = (float*)d_out;
  float* hemb = (float*)d_out + 2 * n;

  // ---- graph build ----
  pcount_kernel<<<NBLK, 256, 0, stream>>>(dstp, cntmat);
  rowsum_kernel<<<NB, 256, 0, stream>>>(cntmat, btotal);
  bucket_scan_kernel<<<1, 1024, 0, stream>>>(btotal, bbase);
  offsets_kernel<<<NB, 256, 0, stream>>>(cntmat, bbase, offmat);
  pscatter_kernel<<<NBLK, 256, 0, stream>>>(srcp, dstp, offmat, store);
  build_kernel<<<NB, 256, 0, stream>>>(btotal, bbase, store, rcp, dinv, csr_src);

  wconv_kernel<<<(128 * 128 + 255) / 256, 256, 0, stream>>>(W1, WT1, 128);
  wconv_kernel<<<(128 * 128 + 255) / 256, 256, 0, stream>>>(W2, WT2, 128);
  wconv_kernel<<<(128 * 64 + 255) / 256, 256, 0, stream>>>(W3, WT3, 64);

  int gemmGrid = (n + 63) / 64;

  if (primary) {
    // layer 1: Tp1 fp8 = (x@W1)*dinv ; partial agg over fp8
    gemm_mfma_kernel<128, false, true><<<gemmGrid, 256, 0, stream>>>(x, WT1, dinv, bufT, n);
    aggp_f8_kernel<<<NGRP * NCHUNK, 256, 0, stream>>>((const uint4*)bufT, rcp, csr_src, Pbuf, n);
    // layer 2: fused reduce+GEMM -> Tp2 fp8
    gemm_fused_kernel<128, true><<<gemmGrid, 256, 0, stream>>>(Pbuf, WT2, dinv, b1, bufT, n);
    aggp_f8_kernel<<<NGRP * NCHUNK, 256, 0, stream>>>((const uint4*)bufT, rcp, csr_src, Pbuf, n);
    // layer 3: fused reduce+GEMM -> Tp3 bf16 [n][64]; bf16 partial agg
    gemm_fused_kernel<64, false><<<gemmGrid, 256, 0, stream>>>(Pbuf, WT3, dinv, b2, bufT, n);
    aggp_bf16_kernel<<<NGRP * NCHUNK, 256, 0, stream>>>((const uint4*)bufT, rcp, csr_src, Pbuf, n);
    reduce3_kernel<<<(n * 8 + 255) / 256, 256, 0, stream>>>(Pbuf, dinv, b3, Wout, bout,
                                                            hemb, outp, n);
  } else {
    // fallback: bf16 everything, direct gather
    ushort* bufHb = Pbuf;
    gemm_mfma_kernel<128, false, false><<<gemmGrid, 256, 0, stream>>>(x, WT1, dinv, bufT, n);
    agg_fb128_kernel<<<(n * 16 + 255) / 256, 256, 0, stream>>>(
        (const uint4*)bufT, rcp, csr_src, dinv, b1, bufHb, n);
    gemm_mfma_kernel<128, true, false><<<gemmGrid, 256, 0, stream>>>(bufHb, WT2, dinv, bufT, n);
    agg_fb128_kernel<<<(n * 16 + 255) / 256, 256, 0, stream>>>(
        (const uint4*)bufT, rcp, csr_src, dinv, b2, bufHb, n);
    gemm_mfma_kernel<64, true, false><<<gemmGrid, 256, 0, stream>>>(bufHb, WT3, dinv, bufT, n);
    agg_fb64_kernel<<<(n * 8 + 255) / 256, 256, 0, stream>>>(
        (const uint4*)bufT, rcp, csr_src, dinv, b3, hemb, Wout, bout, outp, n);
  }
}

// Round 19
// 355.641 us; speedup vs baseline: 1.7400x; 1.0092x over previous
//
#include <hip/hip_runtime.h>

#define NN 100000
#define NE 3200000
#define NB 1021        // buckets
#define BNODES 98      // nodes per bucket (98*1021 >= NN)
#define NBLK 500       // partition blocks (2/CU); CH*NBLK == NE, CH%4==0
#define CH 6400
#define NCHUNK 4       // src chunks of 25000 nodes; 3.2MB fp8 slice < 4MB L2/XCD
#define NPB 200        // nodes per group in aggp
#define NGRP 512       // groups; NGRP*NPB >= NN

typedef unsigned int uint;
typedef unsigned char uchar;
typedef __attribute__((ext_vector_type(8))) short short8v;
typedef __attribute__((ext_vector_type(4))) float float4v;
typedef __attribute__((ext_vector_type(2))) float float2v;
typedef __attribute__((ext_vector_type(4))) uint uint4v;

#if defined(__has_builtin)
#if __has_builtin(__builtin_amdgcn_cvt_pk_f32_fp8) && __has_builtin(__builtin_amdgcn_cvt_pk_fp8_f32)
#define HAVE_FP8_CVT 1
#endif
#endif

// ---- bf16 helpers ----
__device__ inline uint bfr(float f) {
  uint u = __float_as_uint(f);
  return (u + 0x7fffu + ((u >> 16) & 1u)) >> 16;
}
__device__ inline uint pk_bf16(float a, float b) {
  uint r;
  asm("v_cvt_pk_bf16_f32 %0, %1, %2" : "=v"(r) : "v"(a), "v"(b));
  return r;
}
__device__ inline void addq(uint4 q, float* a) {
  uint u[4] = {q.x, q.y, q.z, q.w};
#pragma unroll
  for (int j = 0; j < 4; ++j) {
    a[2 * j]     += __uint_as_float(u[j] << 16);
    a[2 * j + 1] += __uint_as_float(u[j] & 0xffff0000u);
  }
}

// ---- fp8 e4m3 helpers (HI compile-time) ----
#ifndef HAVE_FP8_CVT
__device__ inline float f8dec(uint b) {
  uint s = (b >> 7) & 1u, e = (b >> 3) & 15u, m = b & 7u;
  float v;
  if (e == 0) v = (float)m * 0.001953125f;
  else v = __uint_as_float(((e + 120u) << 23) | (m << 20));
  return s ? -v : v;
}
__device__ inline uint f8enc(float f) {
  uint s = __float_as_uint(f) >> 31;
  float af = fabsf(f);
  if (!(af < 448.f)) af = 448.f;
  uint out;
  if (af < 0.015625f) {
    out = (uint)__float2int_rn(af * 512.f);
  } else {
    uint au = __float_as_uint(af);
    int exp = (int)(au >> 23) - 127;
    uint m = au & 0x7fffffu;
    uint mr = (m >> 20) + (((m & 0xfffffu) > 0x80000u) || (((m & 0xfffffu) == 0x80000u) && ((m >> 20) & 1u)) ? 1u : 0u);
    uint E = (uint)(exp + 7);
    if (mr == 8) { mr = 0; E += 1; }
    if (E > 15) { E = 15; mr = 6; }
    out = (E << 3) | mr;
  }
  return out | (s << 7);
}
#endif
template <bool HI>
__device__ inline float2v f8pk(uint u) {
#ifdef HAVE_FP8_CVT
  return __builtin_amdgcn_cvt_pk_f32_fp8(u, HI);
#else
  float2v r;
  r.x = f8dec(HI ? ((u >> 16) & 255u) : (u & 255u));
  r.y = f8dec(HI ? (u >> 24) : ((u >> 8) & 255u));
  return r;
#endif
}
template <bool HI>
__device__ inline uint f8pk_enc(float a, float b, uint old) {
#ifdef HAVE_FP8_CVT
  return __builtin_amdgcn_cvt_pk_fp8_f32(a, b, old, HI);
#else
  uint two = f8enc(a) | (f8enc(b) << 8);
  return HI ? ((old & 0x0000ffffu) | (two << 16)) : ((old & 0xffff0000u) | two);
#endif
}
__device__ inline void addq_f8(uint4 q, float* a) {
  uint u[4] = {q.x, q.y, q.z, q.w};
#pragma unroll
  for (int j = 0; j < 4; ++j) {
    float2v lo = f8pk<false>(u[j]);
    float2v hi = f8pk<true>(u[j]);
    a[4 * j + 0] += lo.x; a[4 * j + 1] += lo.y;
    a[4 * j + 2] += hi.x; a[4 * j + 3] += hi.y;
  }
}

// non-temporal 16B helpers
__device__ inline uint4 ntload4(const uint4* p) {
  uint4v v = __builtin_nontemporal_load((const uint4v*)p);
  return make_uint4(v.x, v.y, v.z, v.w);
}
__device__ inline void ntstore4(uint4* p, uint4 q) {
  uint4v v = {q.x, q.y, q.z, q.w};
  __builtin_nontemporal_store(v, (uint4v*)p);
}
// chunk = s / 25000 via magic multiply (exact for s < 2^17)
__device__ inline int chunk4(int s) {
  return (int)(((unsigned long long)(uint)s * 171799ull) >> 32);
}

// ---------------- P1: per-block bucket histogram ----------------
__global__ __launch_bounds__(256) void pcount_kernel(const int* __restrict__ dst,
                                                     int* __restrict__ cntmat) {
  __shared__ int cnt[NB];
  int bk = blockIdx.x, tid = threadIdx.x;
  for (int j = tid; j < NB; j += 256) cnt[j] = 0;
  __syncthreads();
  int base = bk * CH;
  for (int i = base + tid * 4; i < base + CH; i += 1024) {
    int4 d4 = *(const int4*)&dst[i];
    atomicAdd(&cnt[(uint)d4.x / (uint)BNODES], 1);
    atomicAdd(&cnt[(uint)d4.y / (uint)BNODES], 1);
    atomicAdd(&cnt[(uint)d4.z / (uint)BNODES], 1);
    atomicAdd(&cnt[(uint)d4.w / (uint)BNODES], 1);
  }
  __syncthreads();
  for (int j = tid; j < NB; j += 256) cntmat[(size_t)j * NBLK + bk] = cnt[j];
}

// ---------------- P2a: bucket totals (NBLK=500 cols, 256 thr) ----------------
__global__ __launch_bounds__(256) void rowsum_kernel(const int* __restrict__ cntmat,
                                                     int* __restrict__ btotal) {
  int b = blockIdx.x, t = threadIdx.x;
  const int* row = cntmat + (size_t)b * NBLK;
  int v = row[t] + ((t + 256 < NBLK) ? row[t + 256] : 0);
#pragma unroll
  for (int off = 32; off >= 1; off >>= 1) v += __shfl_xor(v, off, 64);
  __shared__ int ws[4];
  if ((t & 63) == 0) ws[t >> 6] = v;
  __syncthreads();
  if (t == 0) btotal[b] = ws[0] + ws[1] + ws[2] + ws[3];
}

// ---------------- P2b: scan bucket totals -> bases ----------------
__global__ __launch_bounds__(1024) void bucket_scan_kernel(const int* __restrict__ btotal,
                                                           int* __restrict__ bbase) {
  __shared__ int sh[1024];
  int i = threadIdx.x;
  int v = (i < NB) ? btotal[i] : 0;
  sh[i] = v;
  __syncthreads();
  for (int off = 1; off < 1024; off <<= 1) {
    int t = (i >= off) ? sh[i - off] : 0;
    __syncthreads();
    sh[i] += t;
    __syncthreads();
  }
  if (i < NB) bbase[i] = sh[i] - v;
}

// ---------------- P2c: per-(bucket,block) offsets (pair-scan over 500) ----------------
__global__ __launch_bounds__(256) void offsets_kernel(const int* __restrict__ cntmat,
                                                      const int* __restrict__ bbase,
                                                      int* __restrict__ offmat) {
  __shared__ int sh[256];
  int b = blockIdx.x, t = threadIdx.x;
  const int* row = cntmat + (size_t)b * NBLK;
  int i0 = 2 * t, i1 = 2 * t + 1;
  int v0 = (i0 < NBLK) ? row[i0] : 0;
  int v1 = (i1 < NBLK) ? row[i1] : 0;
  sh[t] = v0 + v1;
  __syncthreads();
  for (int off = 1; off < 256; off <<= 1) {
    int u = (t >= off) ? sh[t - off] : 0;
    __syncthreads();
    sh[t] += u;
    __syncthreads();
  }
  int excl = sh[t] - (v0 + v1);
  int base = bbase[b];
  if (i0 < NBLK) offmat[(size_t)b * NBLK + i0] = base + excl;
  if (i1 < NBLK) offmat[(size_t)b * NBLK + i1] = base + excl + v0;
}

// ---------------- P3: scatter into bucket-contiguous store (packed 4B) ----------------
__global__ __launch_bounds__(256) void pscatter_kernel(const int* __restrict__ src,
                                                       const int* __restrict__ dst,
                                                       const int* __restrict__ offmat,
                                                       int* __restrict__ store) {
  __shared__ int lcur[NB];
  int bk = blockIdx.x, tid = threadIdx.x;
  for (int j = tid; j < NB; j += 256) lcur[j] = offmat[(size_t)j * NBLK + bk];
  __syncthreads();
  int base = bk * CH;
  for (int i = base + tid * 4; i < base + CH; i += 1024) {
    int4 d4 = *(const int4*)&dst[i];
    int4 s4 = *(const int4*)&src[i];
    int dd[4] = {d4.x, d4.y, d4.z, d4.w};
    int ss[4] = {s4.x, s4.y, s4.z, s4.w};
#pragma unroll
    for (int j = 0; j < 4; ++j) {
      uint b = (uint)dd[j] / (uint)BNODES;
      int dl = dd[j] - (int)(b * BNODES);
      int pos = atomicAdd(&lcur[b], 1);
      store[pos] = ss[j] | (dl << 17);
    }
  }
}

// ---------------- P4: per-bucket chunk-major CSR + rcp[c][node] + dinv ----------------
__global__ __launch_bounds__(256) void build_kernel(const int* __restrict__ btotal,
                                                    const int* __restrict__ bbase,
                                                    const int* __restrict__ store,
                                                    int* __restrict__ rcp,
                                                    float* __restrict__ dinv,
                                                    int* __restrict__ csr_src) {
  __shared__ int cnt2[NCHUNK * BNODES];
  __shared__ int excl2[NCHUNK * BNODES];
  int b = blockIdx.x, tid = threadIdx.x;
  int nb0 = b * BNODES;
  int nn = min(BNODES, NN - nb0);
  for (int j = tid; j < NCHUNK * BNODES; j += 256) cnt2[j] = 0;
  __syncthreads();
  int sz = btotal[b], bb = bbase[b];
  const int* bs = store + bb;
  for (int e = tid; e < sz; e += 256) {
    int p = bs[e];
    int dl = (int)((uint)p >> 17);
    int s = p & 0x1FFFF;
    atomicAdd(&cnt2[chunk4(s) * BNODES + dl], 1);
  }
  __syncthreads();
  if (tid == 0) {
    int run = 0;
    for (int j = 0; j < NCHUNK * BNODES; ++j) { excl2[j] = run; run += cnt2[j]; }
  }
  __syncthreads();
  for (int j = tid; j < nn; j += 256) {
    int deg = 0;
#pragma unroll
    for (int c = 0; c < NCHUNK; ++c) {
      int bin = c * BNODES + j;
      rcp[(size_t)c * NN + nb0 + j] = ((bb + excl2[bin]) << 8) | cnt2[bin];
      deg += cnt2[bin];
    }
    dinv[nb0 + j] = rsqrtf((float)(deg + 1));
  }
  __syncthreads();
  for (int j = tid; j < NCHUNK * BNODES; j += 256) cnt2[j] = 0;  // cursors
  __syncthreads();
  for (int e = tid; e < sz; e += 256) {
    int p = bs[e];
    int dl = (int)((uint)p >> 17);
    int s = p & 0x1FFFF;
    int bin = chunk4(s) * BNODES + dl;
    int pos = atomicAdd(&cnt2[bin], 1);
    csr_src[bb + excl2[bin] + pos] = s;
  }
}

// ---------------- W -> bf16 transposed: WT[col][k] = bf16(W[k][col]), K=128 ----------------
__global__ __launch_bounds__(256) void wconv_kernel(const float* __restrict__ W,
                                                    ushort* __restrict__ WT, int N) {
  int idx = blockIdx.x * 256 + threadIdx.x;
  if (idx < 128 * N) {
    int col = idx >> 7;
    int k = idx & 127;
    WT[idx] = (ushort)bfr(W[(size_t)k * N + col]);
  }
}

// ---- shared GEMM epilogue ----
template <int N, bool OUTF8>
__device__ inline void gemm_store(float4v* acc, int row, int lhi,
                                  float dn, void* Cv, int M) {
  if (row >= M) return;
  constexpr int NF = N / 16;
#pragma unroll
  for (int f = 0; f < NF; ++f) {
    float v0 = acc[f][0] * dn, v1 = acc[f][1] * dn;
    float v2 = acc[f][2] * dn, v3 = acc[f][3] * dn;
    int ch = f * 16 + lhi * 4;
    if (OUTF8) {
      uint pk = f8pk_enc<false>(v0, v1, 0u);
      pk = f8pk_enc<true>(v2, v3, pk);
      *(uint*)((uchar*)Cv + (size_t)row * N + ch) = pk;
    } else {
      uint2 st;
      st.x = pk_bf16(v0, v1);
      st.y = pk_bf16(v2, v3);
      *(uint2*)((ushort*)Cv + (size_t)row * N + ch) = st;
    }
  }
}

// ---------------- MFMA GEMM (layer 1) ----------------
template <int N, bool INBF, bool OUTF8>
__global__ __launch_bounds__(256) void gemm_mfma_kernel(const void* __restrict__ Xv,
                                                        const ushort* __restrict__ WT,
                                                        const float* __restrict__ dinv,
                                                        void* __restrict__ C, int M) {
  constexpr int K = 128;
  constexpr int LDK = K + 8;
  __shared__ ushort Xs[64 * LDK];
  __shared__ ushort Ws[N * LDK];
  int tid = threadIdx.x;
  int row0 = blockIdx.x * 64;

#pragma unroll
  for (int i = 0; i < 4; ++i) {
    int idx = (tid + i * 256) * 8;
    int r = idx >> 7, c = idx & 127;
    uint4 v = make_uint4(0, 0, 0, 0);
    if (row0 + r < M) {
      if (INBF) {
        v = *(const uint4*)((const ushort*)Xv + (size_t)(row0 + r) * K + c);
      } else {
        const float* Xf = (const float*)Xv + (size_t)(row0 + r) * K + c;
        float4 f0 = *(const float4*)Xf;
        float4 f1 = *(const float4*)(Xf + 4);
        v.x = pk_bf16(f0.x, f0.y); v.y = pk_bf16(f0.z, f0.w);
        v.z = pk_bf16(f1.x, f1.y); v.w = pk_bf16(f1.z, f1.w);
      }
    }
    *(uint4*)&Xs[r * LDK + c] = v;
  }
#pragma unroll
  for (int i = 0; i < N * K / 2048; ++i) {
    int idx = (tid + i * 256) * 8;
    int col = idx >> 7, k = idx & 127;
    *(uint4*)&Ws[col * LDK + k] = *(const uint4*)&WT[col * K + k];
  }
  __syncthreads();

  int w = tid >> 6, lane = tid & 63;
  int l15 = lane & 15, lhi = lane >> 4;
  constexpr int NF = N / 16;
  float4v acc[NF];
#pragma unroll
  for (int f = 0; f < NF; ++f) acc[f] = (float4v)(0.f);

  const ushort* xbase = &Xs[(w * 16 + l15) * LDK + lhi * 8];
#pragma unroll
  for (int s = 0; s < 4; ++s) {
    short8v xa = *(const short8v*)(xbase + s * 32);
#pragma unroll
    for (int f = 0; f < NF; ++f) {
      short8v wb = *(const short8v*)&Ws[(f * 16 + l15) * LDK + s * 32 + lhi * 8];
      acc[f] = __builtin_amdgcn_mfma_f32_16x16x32_bf16(wb, xa, acc[f], 0, 0, 0);
    }
  }

  int row = row0 + w * 16 + l15;
  float dn = (row < M) ? dinv[row] : 0.f;
  gemm_store<N, OUTF8>(acc, row, lhi, dn, C, M);
}

// ---- XCD-partitioned partial aggregation over fp8 features (128 ch) ----
__global__ __launch_bounds__(256) void aggp_f8_kernel(const uint4* __restrict__ Tq,
                                                      const int* __restrict__ rcp,
                                                      const int* __restrict__ csr_src,
                                                      ushort* __restrict__ P, int n) {
  int c = blockIdx.x & 3;
  int g = blockIdx.x >> 2;
  constexpr int SPB = 32;
  int lane = threadIdx.x & 7;
  int slot = threadIdx.x >> 3;
  uint4* Pq = (uint4*)P + (size_t)c * n * 16;
  const int* rcp_c = rcp + (size_t)c * NN;
  for (int it = 0; it < (NPB + SPB - 1) / SPB; ++it) {
    int off = it * SPB + slot;
    if (off >= NPB) break;
    int node = g * NPB + off;
    if (node >= n) break;
    int v = rcp_c[node];
    int lo = v >> 8, hi = lo + (v & 255);
    float a[16];
#pragma unroll
    for (int j = 0; j < 16; ++j) a[j] = 0.f;
    if (chunk4(node) == c) addq_f8(Tq[(size_t)node * 8 + lane], a);
    int e = lo;
    for (; e + 4 <= hi; e += 4) {
      int s0 = csr_src[e], s1 = csr_src[e + 1];
      int s2 = csr_src[e + 2], s3 = csr_src[e + 3];
      uint4 q0 = Tq[(size_t)s0 * 8 + lane];
      uint4 q1 = Tq[(size_t)s1 * 8 + lane];
      uint4 q2 = Tq[(size_t)s2 * 8 + lane];
      uint4 q3 = Tq[(size_t)s3 * 8 + lane];
      addq_f8(q0, a); addq_f8(q1, a); addq_f8(q2, a); addq_f8(q3, a);
    }
    for (; e < hi; ++e) addq_f8(Tq[(size_t)csr_src[e] * 8 + lane], a);
    uint4 st0, st1;
    st0.x = pk_bf16(a[0], a[1]);  st0.y = pk_bf16(a[2], a[3]);
    st0.z = pk_bf16(a[4], a[5]);  st0.w = pk_bf16(a[6], a[7]);
    st1.x = pk_bf16(a[8], a[9]);  st1.y = pk_bf16(a[10], a[11]);
    st1.z = pk_bf16(a[12], a[13]); st1.w = pk_bf16(a[14], a[15]);
    ntstore4(&Pq[(size_t)node * 16 + lane * 2], st0);
    ntstore4(&Pq[(size_t)node * 16 + lane * 2 + 1], st1);
  }
}

// ---- XCD-partitioned partial aggregation over bf16 features (layer 3, 64 ch) ----
__global__ __launch_bounds__(256) void aggp_bf16_kernel(const uint4* __restrict__ Tq,
                                                        const int* __restrict__ rcp,
                                                        const int* __restrict__ csr_src,
                                                        ushort* __restrict__ P, int n) {
  int c = blockIdx.x & 3;
  int g = blockIdx.x >> 2;
  constexpr int LPN = 8, SPB = 32;
  int lane = threadIdx.x & 7;
  int slot = threadIdx.x >> 3;
  uint4* Pq = (uint4*)P + (size_t)c * n * LPN;
  const int* rcp_c = rcp + (size_t)c * NN;
  for (int it = 0; it < (NPB + SPB - 1) / SPB; ++it) {
    int off = it * SPB + slot;
    if (off >= NPB) break;
    int node = g * NPB + off;
    if (node >= n) break;
    int v = rcp_c[node];
    int lo = v >> 8, hi = lo + (v & 255);
    float a[8];
#pragma unroll
    for (int j = 0; j < 8; ++j) a[j] = 0.f;
    if (chunk4(node) == c) addq(Tq[(size_t)node * LPN + lane], a);
    int e = lo;
    for (; e + 4 <= hi; e += 4) {
      int s0 = csr_src[e], s1 = csr_src[e + 1];
      int s2 = csr_src[e + 2], s3 = csr_src[e + 3];
      uint4 q0 = Tq[(size_t)s0 * LPN + lane];
      uint4 q1 = Tq[(size_t)s1 * LPN + lane];
      uint4 q2 = Tq[(size_t)s2 * LPN + lane];
      uint4 q3 = Tq[(size_t)s3 * LPN + lane];
      addq(q0, a); addq(q1, a); addq(q2, a); addq(q3, a);
    }
    for (; e < hi; ++e) addq(Tq[(size_t)csr_src[e] * LPN + lane], a);
    uint4 st;
    st.x = pk_bf16(a[0], a[1]);
    st.y = pk_bf16(a[2], a[3]);
    st.z = pk_bf16(a[4], a[5]);
    st.w = pk_bf16(a[6], a[7]);
    ntstore4(&Pq[(size_t)node * LPN + lane], st);
  }
}

// ---- fused GEMM: h = relu(dn*sum_c P_c + b); C = (h @ W)*dinv ----
template <int N, bool OUTF8>
__global__ __launch_bounds__(256) void gemm_fused_kernel(const ushort* __restrict__ P,
                                                         const ushort* __restrict__ WT,
                                                         const float* __restrict__ dinv,
                                                         const float* __restrict__ bias,
                                                         void* __restrict__ C, int M) {
  constexpr int K = 128;
  constexpr int LDK = K + 8;
  __shared__ ushort Xs[64 * LDK];
  __shared__ ushort Ws[N * LDK];
  int tid = threadIdx.x;
  int row0 = blockIdx.x * 64;
  const uint4* Pq = (const uint4*)P;
  size_t ps = (size_t)M * 16;

  {
    int l = tid & 15;
    int rb = tid >> 4;
    float4 bv0 = *(const float4*)&bias[l * 8];
    float4 bv1 = *(const float4*)&bias[l * 8 + 4];
    float bb[8] = {bv0.x, bv0.y, bv0.z, bv0.w, bv1.x, bv1.y, bv1.z, bv1.w};
#pragma unroll
    for (int i = 0; i < 4; ++i) {
      int r = rb + i * 16;
      int row = row0 + r;
      uint4 st = make_uint4(0, 0, 0, 0);
      if (row < M) {
        float a[8];
#pragma unroll
        for (int j = 0; j < 8; ++j) a[j] = 0.f;
#pragma unroll
        for (int c = 0; c < NCHUNK; ++c)
          addq(ntload4(&Pq[(size_t)c * ps + (size_t)row * 16 + l]), a);
        float dn = dinv[row];
        float h[8];
#pragma unroll
        for (int j = 0; j < 8; ++j) h[j] = fmaxf(fmaf(dn, a[j], bb[j]), 0.f);
        st.x = pk_bf16(h[0], h[1]);
        st.y = pk_bf16(h[2], h[3]);
        st.z = pk_bf16(h[4], h[5]);
        st.w = pk_bf16(h[6], h[7]);
      }
      *(uint4*)&Xs[r * LDK + l * 8] = st;
    }
  }
#pragma unroll
  for (int i = 0; i < N * K / 2048; ++i) {
    int idx = (tid + i * 256) * 8;
    int col = idx >> 7, k = idx & 127;
    *(uint4*)&Ws[col * LDK + k] = *(const uint4*)&WT[col * K + k];
  }
  __syncthreads();

  int w = tid >> 6, lane = tid & 63;
  int l15 = lane & 15, lhi = lane >> 4;
  constexpr int NF = N / 16;
  float4v acc[NF];
#pragma unroll
  for (int f = 0; f < NF; ++f) acc[f] = (float4v)(0.f);

  const ushort* xbase = &Xs[(w * 16 + l15) * LDK + lhi * 8];
#pragma unroll
  for (int s = 0; s < 4; ++s) {
    short8v xa = *(const short8v*)(xbase + s * 32);
#pragma unroll
    for (int f = 0; f < NF; ++f) {
      short8v wb = *(const short8v*)&Ws[(f * 16 + l15) * LDK + s * 32 + lhi * 8];
      acc[f] = __builtin_amdgcn_mfma_f32_16x16x32_bf16(wb, xa, acc[f], 0, 0, 0);
    }
  }

  int row = row0 + w * 16 + l15;
  float dn = (row < M) ? dinv[row] : 0.f;
  gemm_store<N, OUTF8>(acc, row, lhi, dn, C, M);
}

// ---- layer-3 reduce ----
__global__ __launch_bounds__(256) void reduce3_kernel(const ushort* __restrict__ P,
                                                      const float* __restrict__ dinv,
                                                      const float* __restrict__ b3,
                                                      const float* __restrict__ Wout,
                                                      const float* __restrict__ bout,
                                                      float* __restrict__ Hemb,
                                                      float* __restrict__ Out, int n) {
  int t = blockIdx.x * 256 + threadIdx.x;
  int node = t >> 3;
  int lane = t & 7;
  if (node >= n) return;
  const uint4* Pq = (const uint4*)P;
  size_t ps = (size_t)n * 8;
  float a[8];
#pragma unroll
  for (int j = 0; j < 8; ++j) a[j] = 0.f;
#pragma unroll
  for (int c = 0; c < NCHUNK; ++c) addq(ntload4(&Pq[(size_t)c * ps + (size_t)node * 8 + lane]), a);
  float dn = dinv[node];
  float4 bv0 = *(const float4*)&b3[lane * 8];
  float4 bv1 = *(const float4*)&b3[lane * 8 + 4];
  float bb[8] = {bv0.x, bv0.y, bv0.z, bv0.w, bv1.x, bv1.y, bv1.z, bv1.w};
  float h[8];
#pragma unroll
  for (int j = 0; j < 8; ++j) h[j] = fmaf(dn, a[j], bb[j]);
  float* Hrow = &Hemb[(size_t)node * 64 + lane * 8];
  *(float4*)&Hrow[0] = make_float4(h[0], h[1], h[2], h[3]);
  *(float4*)&Hrow[4] = make_float4(h[4], h[5], h[6], h[7]);
  int k0 = 8 * lane;
  float p0 = 0.f, p1 = 0.f;
#pragma unroll
  for (int j = 0; j < 8; ++j) {
    p0 = fmaf(h[j], Wout[(k0 + j) * 2 + 0], p0);
    p1 = fmaf(h[j], Wout[(k0 + j) * 2 + 1], p1);
  }
#pragma unroll
  for (int off = 4; off >= 1; off >>= 1) {
    p0 += __shfl_xor(p0, off, 8);
    p1 += __shfl_xor(p1, off, 8);
  }
  if (lane == 0) {
    Out[(size_t)node * 2 + 0] = p0 + bout[0];
    Out[(size_t)node * 2 + 1] = p1 + bout[1];
  }
}

// ---- fallback (small ws): direct bf16 gather agg over rcp[c][node] segments ----
__global__ __launch_bounds__(256) void agg_fb128_kernel(const uint4* __restrict__ Tq,
                                                        const int* __restrict__ rcp,
                                                        const int* __restrict__ csr_src,
                                                        const float* __restrict__ dinv,
                                                        const float* __restrict__ bias,
                                                        ushort* __restrict__ H, int n) {
  int t = blockIdx.x * 256 + threadIdx.x;
  int node = t >> 4;
  int lane = t & 15;
  if (node >= n) return;
  float dn = dinv[node];
  float a0[8], a1[8], a2[8], a3[8];
#pragma unroll
  for (int c = 0; c < 8; ++c) { a0[c] = 0.f; a1[c] = 0.f; a2[c] = 0.f; a3[c] = 0.f; }
  addq(Tq[(size_t)node * 16 + lane], a0);
#pragma unroll
  for (int c = 0; c < NCHUNK; ++c) {
    int v = rcp[(size_t)c * NN + node];
    int lo = v >> 8, hi = lo + (v & 255);
    int e = lo;
    for (; e + 4 <= hi; e += 4) {
      uint4 q0 = Tq[(size_t)csr_src[e] * 16 + lane];
      uint4 q1 = Tq[(size_t)csr_src[e + 1] * 16 + lane];
      uint4 q2 = Tq[(size_t)csr_src[e + 2] * 16 + lane];
      uint4 q3 = Tq[(size_t)csr_src[e + 3] * 16 + lane];
      addq(q0, a0); addq(q1, a1); addq(q2, a2); addq(q3, a3);
    }
    for (; e < hi; ++e) addq(Tq[(size_t)csr_src[e] * 16 + lane], a0);
  }
  float4 bv0 = *(const float4*)&bias[lane * 8];
  float4 bv1 = *(const float4*)&bias[lane * 8 + 4];
  float bb[8] = {bv0.x, bv0.y, bv0.z, bv0.w, bv1.x, bv1.y, bv1.z, bv1.w};
  float h[8];
#pragma unroll
  for (int c = 0; c < 8; ++c) {
    h[c] = fmaf(dn, (a0[c] + a1[c]) + (a2[c] + a3[c]), bb[c]);
    h[c] = fmaxf(h[c], 0.f);
  }
  uint4 st;
  st.x = pk_bf16(h[0], h[1]);
  st.y = pk_bf16(h[2], h[3]);
  st.z = pk_bf16(h[4], h[5]);
  st.w = pk_bf16(h[6], h[7]);
  *(uint4*)&H[(size_t)node * 128 + lane * 8] = st;
}

__global__ __launch_bounds__(256) void agg_fb64_kernel(const uint4* __restrict__ Tq,
                                                       const int* __restrict__ rcp,
                                                       const int* __restrict__ csr_src,
                                                       const float* __restrict__ dinv,
                                                       const float* __restrict__ bias,
                                                       float* __restrict__ H,
                                                       const float* __restrict__ Wout,
                                                       const float* __restrict__ bout,
                                                       float* __restrict__ Out, int n) {
  int t = blockIdx.x * 256 + threadIdx.x;
  int node = t >> 3;
  int lane = t & 7;
  if (node >= n) return;
  float dn = dinv[node];
  float a0[8], a1[8], a2[8], a3[8];
#pragma unroll
  for (int c = 0; c < 8; ++c) { a0[c] = 0.f; a1[c] = 0.f; a2[c] = 0.f; a3[c] = 0.f; }
  addq(Tq[(size_t)node * 8 + lane], a0);
#pragma unroll
  for (int c = 0; c < NCHUNK; ++c) {
    int v = rcp[(size_t)c * NN + node];
    int lo = v >> 8, hi = lo + (v & 255);
    int e = lo;
    for (; e + 4 <= hi; e += 4) {
      uint4 q0 = Tq[(size_t)csr_src[e] * 8 + lane];
      uint4 q1 = Tq[(size_t)csr_src[e + 1] * 8 + lane];
      uint4 q2 = Tq[(size_t)csr_src[e + 2] * 8 + lane];
      uint4 q3 = Tq[(size_t)csr_src[e + 3] * 8 + lane];
      addq(q0, a0); addq(q1, a1); addq(q2, a2); addq(q3, a3);
    }
    for (; e < hi; ++e) addq(Tq[(size_t)csr_src[e] * 8 + lane], a0);
  }
  float4 bv0 = *(const float4*)&bias[lane * 8];
  float4 bv1 = *(const float4*)&bias[lane * 8 + 4];
  float bb[8] = {bv0.x, bv0.y, bv0.z, bv0.w, bv1.x, bv1.y, bv1.z, bv1.w};
  float h[8];
#pragma unroll
  for (int c = 0; c < 8; ++c)
    h[c] = fmaf(dn, (a0[c] + a1[c]) + (a2[c] + a3[c]), bb[c]);
  float* Hrow = &H[(size_t)node * 64 + lane * 8];
  *(float4*)&Hrow[0] = make_float4(h[0], h[1], h[2], h[3]);
  *(float4*)&Hrow[4] = make_float4(h[4], h[5], h[6], h[7]);
  int k0 = 8 * lane;
  float p0 = 0.f, p1 = 0.f;
#pragma unroll
  for (int c = 0; c < 8; ++c) {
    p0 = fmaf(h[c], Wout[(k0 + c) * 2 + 0], p0);
    p1 = fmaf(h[c], Wout[(k0 + c) * 2 + 1], p1);
  }
#pragma unroll
  for (int off = 4; off >= 1; off >>= 1) {
    p0 += __shfl_xor(p0, off, 8);
    p1 += __shfl_xor(p1, off, 8);
  }
  if (lane == 0) {
    Out[(size_t)node * 2 + 0] = p0 + bout[0];
    Out[(size_t)node * 2 + 1] = p1 + bout[1];
  }
}

extern "C" void kernel_launch(void* const* d_in, const int* in_sizes, int n_in,
                              void* d_out, int out_size, void* d_ws, size_t ws_size,
                              hipStream_t stream) {
  const float* x    = (const float*)d_in[0];
  const int*   ei   = (const int*)d_in[1];
  const float* W1   = (const float*)d_in[2];
  const float* b1   = (const float*)d_in[3];
  const float* W2   = (const float*)d_in[4];
  const float* b2   = (const float*)d_in[5];
  const float* W3   = (const float*)d_in[6];
  const float* b3   = (const float*)d_in[7];
  const float* Wout = (const float*)d_in[8];
  const float* bout = (const float*)d_in[9];

  const int n = NN, E = NE;
  const int* srcp = ei;
  const int* dstp = ei + E;

  char* ws = (char*)d_ws;
  int*    cntmat  = (int*)(ws + 0);            // NB*500*4 = 2,042,000 -> pad 2,097,152
  int*    btotal  = (int*)(ws + 2097152);      // -> 2,101,248
  int*    bbase   = (int*)(ws + 2101248);      // -> 2,105,344
  int*    offmat  = (int*)(ws + 2105344);      // +2,042,000 -> 4,147,344
  float*  dinv    = (float*)(ws + 4147344);    // +400,000 -> 4,547,344
  int*    rcp     = (int*)(ws + 4547344);      // [c][node] 1.6MB -> 6,147,344
  int*    csr_src = (int*)(ws + 6147344);      // 12.8MB -> 18,947,344
  ushort* WT1     = (ushort*)(ws + 18947344);  // 32KB
  ushort* WT2     = (ushort*)(ws + 18980112);  // 32KB
  ushort* WT3     = (ushort*)(ws + 19012880);  // 16KB -> 19,029,264
  char*   bufT    = ws + 19029264;             // 25.6MB -> 44,629,264
  ushort* Pbuf    = (ushort*)(ws + 44629264);  // 4 x 25.6MB -> 147,029,264
  int*    store   = (int*)(ws + 44629264);     // aliases Pbuf (dead after build)

  const size_t PRIMARY_NEED = 147029264ull;
  bool primary = ws_size >= PRIMARY_NEED;

  float* outp = (float*)d_out;
  float* hemb = (float*)d_out + 2 * n;

  // ---- graph build ----
  pcount_kernel<<<NBLK, 256, 0, stream>>>(dstp, cntmat);
  rowsum_kernel<<<NB, 256, 0, stream>>>(cntmat, btotal);
  bucket_scan_kernel<<<1, 1024, 0, stream>>>(btotal, bbase);
  offsets_kernel<<<NB, 256, 0, stream>>>(cntmat, bbase, offmat);
  pscatter_kernel<<<NBLK, 256, 0, stream>>>(srcp, dstp, offmat, store);
  build_kernel<<<NB, 256, 0, stream>>>(btotal, bbase, store, rcp, dinv, csr_src);

  wconv_kernel<<<(128 * 128 + 255) / 256, 256, 0, stream>>>(W1, WT1, 128);
  wconv_kernel<<<(128 * 128 + 255) / 256, 256, 0, stream>>>(W2, WT2, 128);
  wconv_kernel<<<(128 * 64 + 255) / 256, 256, 0, stream>>>(W3, WT3, 64);

  int gemmGrid = (n + 63) / 64;

  if (primary) {
    gemm_mfma_kernel<128, false, true><<<gemmGrid, 256, 0, stream>>>(x, WT1, dinv, bufT, n);
    aggp_f8_kernel<<<NGRP * NCHUNK, 256, 0, stream>>>((const uint4*)bufT, rcp, csr_src, Pbuf, n);
    gemm_fused_kernel<128, true><<<gemmGrid, 256, 0, stream>>>(Pbuf, WT2, dinv, b1, bufT, n);
    aggp_f8_kernel<<<NGRP * NCHUNK, 256, 0, stream>>>((const uint4*)bufT, rcp, csr_src, Pbuf, n);
    gemm_fused_kernel<64, false><<<gemmGrid, 256, 0, stream>>>(Pbuf, WT3, dinv, b2, bufT, n);
    aggp_bf16_kernel<<<NGRP * NCHUNK, 256, 0, stream>>>((const uint4*)bufT, rcp, csr_src, Pbuf, n);
    reduce3_kernel<<<(n * 8 + 255) / 256, 256, 0, stream>>>(Pbuf, dinv, b3, Wout, bout,
                                                            hemb, outp, n);
  } else {
    ushort* bufHb = Pbuf;
    gemm_mfma_kernel<128, false, false><<<gemmGrid, 256, 0, stream>>>(x, WT1, dinv, bufT, n);
    agg_fb128_kernel<<<(n * 16 + 255) / 256, 256, 0, stream>>>(
        (const uint4*)bufT, rcp, csr_src, dinv, b1, bufHb, n);
    gemm_mfma_kernel<128, true, false><<<gemmGrid, 256, 0, stream>>>(bufHb, WT2, dinv, bufT, n);
    agg_fb128_kernel<<<(n * 16 + 255) / 256, 256, 0, stream>>>(
        (const uint4*)bufT, rcp, csr_src, dinv, b2, bufHb, n);
    gemm_mfma_kernel<64, true, false><<<gemmGrid, 256, 0, stream>>>(bufHb, WT3, dinv, bufT, n);
    agg_fb64_kernel<<<(n * 8 + 255) / 256, 256, 0, stream>>>(
        (const uint4*)bufT, rcp, csr_src, dinv, b3, hemb, Wout, bout, outp, n);
  }
}